// Round 2
// baseline (1423.149 us; speedup 1.0000x reference)
//
#include <hip/hip_runtime.h>

#define N_NODES 100000
#define F_IN 128
#define H1 64
#define H2 32
#define NCLS 10

// ---------------------------------------------------------------- degree
__global__ void deg_count_kernel(const int* __restrict__ dst, int E,
                                 float* __restrict__ deg) {
    int e = blockIdx.x * blockDim.x + threadIdx.x;
    if (e < E) atomicAdd(&deg[dst[e]], 1.0f);
}

__global__ void dinv_kernel(float* __restrict__ deg_dinv, int n) {
    int i = blockIdx.x * blockDim.x + threadIdx.x;
    if (i < n) deg_dinv[i] = rsqrtf(deg_dinv[i] + 1.0f);
}

// ---------------------------------------------------------------- GEMM 1: [N,128] @ [128,64]
__global__ __launch_bounds__(256) void gemm1_kernel(const float* __restrict__ X,
                                                    const float* __restrict__ W,
                                                    float* __restrict__ H) {
    __shared__ float Ws[F_IN * H1];   // 32 KB
    __shared__ float Xs[4][F_IN];     // 2 KB
    int r0 = blockIdx.x * 4;
    for (int idx = threadIdx.x; idx < F_IN * H1; idx += 256) Ws[idx] = W[idx];
    for (int idx = threadIdx.x; idx < 4 * F_IN; idx += 256) {
        int r = idx / F_IN, k = idx - r * F_IN;
        int row = r0 + r;
        Xs[r][k] = (row < N_NODES) ? X[(long long)row * F_IN + k] : 0.0f;
    }
    __syncthreads();
    int col = threadIdx.x & 63;
    int r = threadIdx.x >> 6;
    int row = r0 + r;
    if (row < N_NODES) {
        float acc = 0.0f;
        #pragma unroll 8
        for (int k = 0; k < F_IN; ++k) acc += Xs[r][k] * Ws[k * H1 + col];
        H[(long long)row * H1 + col] = acc;
    }
}

// ---------------------------------------------------------------- GEMM 2: [N,64] @ [64,32]
__global__ __launch_bounds__(256) void gemm2_kernel(const float* __restrict__ X,
                                                    const float* __restrict__ W,
                                                    float* __restrict__ H) {
    __shared__ float Ws[H1 * H2];    // 8 KB
    __shared__ float Xs[8][H1];      // 2 KB
    int r0 = blockIdx.x * 8;
    for (int idx = threadIdx.x; idx < H1 * H2; idx += 256) Ws[idx] = W[idx];
    for (int idx = threadIdx.x; idx < 8 * H1; idx += 256) {
        int r = idx / H1, k = idx - r * H1;
        int row = r0 + r;
        Xs[r][k] = (row < N_NODES) ? X[(long long)row * H1 + k] : 0.0f;
    }
    __syncthreads();
    int col = threadIdx.x & 31;
    int r = threadIdx.x >> 5;
    int row = r0 + r;
    if (row < N_NODES) {
        float acc = 0.0f;
        #pragma unroll
        for (int k = 0; k < H1; ++k) acc += Xs[r][k] * Ws[k * H2 + col];
        H[(long long)row * H2 + col] = acc;
    }
}

// ---------------------------------------------------------------- edge aggregation (push, atomic)
// one thread per (edge, feature); F is a power of 2
template <int F, int LOGF>
__global__ __launch_bounds__(256) void agg_kernel(const float* __restrict__ h,
                                                  const int* __restrict__ src,
                                                  const int* __restrict__ dst,
                                                  const float* __restrict__ dinv,
                                                  int E, float* __restrict__ agg) {
    unsigned long long tid =
        (unsigned long long)blockIdx.x * blockDim.x + threadIdx.x;
    int e = (int)(tid >> LOGF);
    int f = (int)(tid & (F - 1));
    if (e < E) {
        int s = src[e];
        int d = dst[e];
        float norm = dinv[s] * dinv[d];
        atomicAdd(&agg[(long long)d * F + f],
                  h[(long long)s * F + f] * norm);
    }
}

// ---------------------------------------------------------------- self-loop + bias + relu (in place on agg)
template <int F, int LOGF>
__global__ __launch_bounds__(256) void epilogue_kernel(const float* __restrict__ h,
                                                       const float* __restrict__ dinv,
                                                       const float* __restrict__ b,
                                                       float* __restrict__ agg, int n) {
    unsigned long long tid =
        (unsigned long long)blockIdx.x * blockDim.x + threadIdx.x;
    int i = (int)(tid >> LOGF);
    int f = (int)(tid & (F - 1));
    if (i < n) {
        float di = dinv[i];
        float v = agg[tid] + h[tid] * di * di + b[f];
        agg[tid] = v > 0.0f ? v : 0.0f;
    }
}

// ---------------------------------------------------------------- classifier + log_softmax
__global__ __launch_bounds__(256) void final_kernel(const float* __restrict__ X2,
                                                    const float* __restrict__ Wc,
                                                    const float* __restrict__ bc,
                                                    float* __restrict__ out) {
    __shared__ float Ws[H2 * NCLS];   // 320 floats > 256 threads: MUST loop
    __shared__ float bs[NCLS];
    for (int idx = threadIdx.x; idx < H2 * NCLS; idx += 256) Ws[idx] = Wc[idx];
    if (threadIdx.x < NCLS) bs[threadIdx.x] = bc[threadIdx.x];
    __syncthreads();
    int i = blockIdx.x * blockDim.x + threadIdx.x;
    if (i >= N_NODES) return;
    float x[H2];
    #pragma unroll
    for (int k = 0; k < H2; ++k) x[k] = X2[(long long)i * H2 + k];
    float lg[NCLS];
    #pragma unroll
    for (int c = 0; c < NCLS; ++c) {
        float acc = bs[c];
        #pragma unroll
        for (int k = 0; k < H2; ++k) acc += x[k] * Ws[k * NCLS + c];
        lg[c] = acc;
    }
    float m = lg[0];
    #pragma unroll
    for (int c = 1; c < NCLS; ++c) m = fmaxf(m, lg[c]);
    float s = 0.0f;
    #pragma unroll
    for (int c = 0; c < NCLS; ++c) s += expf(lg[c] - m);
    float lse = m + logf(s);
    #pragma unroll
    for (int c = 0; c < NCLS; ++c) out[(long long)i * NCLS + c] = lg[c] - lse;
}

// ----------------------------------------------------------------
extern "C" void kernel_launch(void* const* d_in, const int* in_sizes, int n_in,
                              void* d_out, int out_size, void* d_ws, size_t ws_size,
                              hipStream_t stream) {
    const float* feature = (const float*)d_in[0];
    const int*   eidx    = (const int*)d_in[1];
    const float* W1      = (const float*)d_in[2];
    const float* b1      = (const float*)d_in[3];
    const float* W2      = (const float*)d_in[4];
    const float* b2      = (const float*)d_in[5];
    const float* Wc      = (const float*)d_in[6];
    const float* bc      = (const float*)d_in[7];
    float* out = (float*)d_out;

    const int E = in_sizes[1] / 2;
    const int* src = eidx;
    const int* dst = eidx + E;

    // workspace layout (floats):
    //   dinv  [N]            (first used as degree accumulator)
    //   agg1  [N*64]         (becomes x1 after epilogue1)
    //   scratch region [N*64] reused as: h1 first, then (agg2 [N*32] | h2 [N*32])
    float* ws   = (float*)d_ws;
    float* dinv = ws;
    float* agg1 = dinv + N_NODES;
    float* h1   = agg1 + (size_t)N_NODES * H1;
    float* agg2 = h1;                              // reuse after h1 is dead
    float* h2   = h1 + (size_t)N_NODES * H2;

    // zero deg + agg1 (contiguous)
    hipMemsetAsync(dinv, 0, (size_t)N_NODES * (1 + H1) * sizeof(float), stream);

    // degree -> dinv
    deg_count_kernel<<<(E + 255) / 256, 256, 0, stream>>>(dst, E, dinv);
    dinv_kernel<<<(N_NODES + 255) / 256, 256, 0, stream>>>(dinv, N_NODES);

    // layer 1
    gemm1_kernel<<<(N_NODES + 3) / 4, 256, 0, stream>>>(feature, W1, h1);
    {
        unsigned long long total = (unsigned long long)E * H1;
        unsigned int grid = (unsigned int)((total + 255) / 256);
        agg_kernel<H1, 6><<<grid, 256, 0, stream>>>(h1, src, dst, dinv, E, agg1);
    }
    {
        unsigned long long total = (unsigned long long)N_NODES * H1;
        unsigned int grid = (unsigned int)((total + 255) / 256);
        epilogue_kernel<H1, 6><<<grid, 256, 0, stream>>>(h1, dinv, b1, agg1, N_NODES);
    }

    // h1 dead from here; agg2/h2 reuse its region (stream order guarantees safety)
    hipMemsetAsync(agg2, 0, (size_t)N_NODES * H2 * sizeof(float), stream);

    // layer 2
    gemm2_kernel<<<(N_NODES + 7) / 8, 256, 0, stream>>>(agg1, W2, h2);
    {
        unsigned long long total = (unsigned long long)E * H2;
        unsigned int grid = (unsigned int)((total + 255) / 256);
        agg_kernel<H2, 5><<<grid, 256, 0, stream>>>(h2, src, dst, dinv, E, agg2);
    }
    {
        unsigned long long total = (unsigned long long)N_NODES * H2;
        unsigned int grid = (unsigned int)((total + 255) / 256);
        epilogue_kernel<H2, 5><<<grid, 256, 0, stream>>>(h2, dinv, b2, agg2, N_NODES);
    }

    // classifier + log_softmax
    final_kernel<<<(N_NODES + 255) / 256, 256, 0, stream>>>(agg2, Wc, bc, out);
}

// Round 3
// 873.807 us; speedup vs baseline: 1.6287x; 1.6287x over previous
//
#include <hip/hip_runtime.h>

#define N_NODES 100000
#define F_IN 128
#define H1 64
#define H2 32
#define NCLS 10

// ---------------------------------------------------------------- degree histogram (int)
__global__ void deg_count_kernel(const int* __restrict__ dst, int E,
                                 int* __restrict__ deg) {
    int e = blockIdx.x * blockDim.x + threadIdx.x;
    if (e < E) atomicAdd(&deg[dst[e]], 1);
}

__global__ void dinv_kernel(const int* __restrict__ deg, float* __restrict__ dinv, int n) {
    int i = blockIdx.x * blockDim.x + threadIdx.x;
    if (i < n) dinv[i] = rsqrtf((float)deg[i] + 1.0f);
}

// ---------------------------------------------------------------- row offsets: wave scan + one atomic per 64 nodes
// deg_cursor: in = degree, out = row_start (serves as scatter cursor, then row_end)
__global__ __launch_bounds__(256) void rowstart_kernel(int* __restrict__ deg_cursor,
                                                       int* __restrict__ row_start,
                                                       unsigned int* __restrict__ counter) {
    int i = blockIdx.x * 256 + threadIdx.x;
    int lane = threadIdx.x & 63;
    int d = (i < N_NODES) ? deg_cursor[i] : 0;
    int x = d;
    #pragma unroll
    for (int off = 1; off < 64; off <<= 1) {
        int y = __shfl_up(x, off);
        if (lane >= off) x += y;
    }
    int total = __shfl(x, 63);               // wave-inclusive total
    unsigned int base = 0;
    if (lane == 0) base = atomicAdd(counter, (unsigned int)total);
    base = __shfl(base, 0);
    int start = (int)base + (x - d);         // exclusive scan + wave base
    if (i < N_NODES) { row_start[i] = start; deg_cursor[i] = start; }
}

// ---------------------------------------------------------------- scatter edges into CSR by dst
__global__ void scatter_kernel(const int* __restrict__ src, const int* __restrict__ dst,
                               int E, int* __restrict__ cursor, int* __restrict__ csr) {
    int e = blockIdx.x * blockDim.x + threadIdx.x;
    if (e < E) {
        int d = dst[e];
        int pos = atomicAdd(&cursor[d], 1);
        csr[pos] = src[e];
    }
}

// ---------------------------------------------------------------- GEMM 1: [N,128] @ [128,64]
__global__ __launch_bounds__(256) void gemm1_kernel(const float* __restrict__ X,
                                                    const float* __restrict__ W,
                                                    float* __restrict__ H) {
    __shared__ float Ws[F_IN * H1];   // 32 KB
    __shared__ float Xs[4][F_IN];     // 2 KB
    int r0 = blockIdx.x * 4;
    for (int idx = threadIdx.x; idx < F_IN * H1; idx += 256) Ws[idx] = W[idx];
    for (int idx = threadIdx.x; idx < 4 * F_IN; idx += 256) {
        int r = idx / F_IN, k = idx - r * F_IN;
        int row = r0 + r;
        Xs[r][k] = (row < N_NODES) ? X[(long long)row * F_IN + k] : 0.0f;
    }
    __syncthreads();
    int col = threadIdx.x & 63;
    int r = threadIdx.x >> 6;
    int row = r0 + r;
    if (row < N_NODES) {
        float acc = 0.0f;
        #pragma unroll 8
        for (int k = 0; k < F_IN; ++k) acc += Xs[r][k] * Ws[k * H1 + col];
        H[(long long)row * H1 + col] = acc;
    }
}

// ---------------------------------------------------------------- GEMM 2: [N,64] @ [64,32]
__global__ __launch_bounds__(256) void gemm2_kernel(const float* __restrict__ X,
                                                    const float* __restrict__ W,
                                                    float* __restrict__ H) {
    __shared__ float Ws[H1 * H2];    // 8 KB
    __shared__ float Xs[8][H1];      // 2 KB
    int r0 = blockIdx.x * 8;
    for (int idx = threadIdx.x; idx < H1 * H2; idx += 256) Ws[idx] = W[idx];
    for (int idx = threadIdx.x; idx < 8 * H1; idx += 256) {
        int r = idx / H1, k = idx - r * H1;
        int row = r0 + r;
        Xs[r][k] = (row < N_NODES) ? X[(long long)row * H1 + k] : 0.0f;
    }
    __syncthreads();
    int col = threadIdx.x & 31;
    int r = threadIdx.x >> 5;
    int row = r0 + r;
    if (row < N_NODES) {
        float acc = 0.0f;
        #pragma unroll
        for (int k = 0; k < H1; ++k) acc += Xs[r][k] * Ws[k * H2 + col];
        H[(long long)row * H2 + col] = acc;
    }
}

// ---------------------------------------------------------------- pull aggregation, F=64: one wave per node
// x_out[i] = relu( dinv[i] * sum_s h[s]*dinv[s]  +  h[i]*dinv[i]^2  + b )
__global__ __launch_bounds__(256) void pull1_kernel(const float* __restrict__ h,
                                                    const int* __restrict__ csr,
                                                    const int* __restrict__ row_start,
                                                    const int* __restrict__ row_end,
                                                    const float* __restrict__ dinv,
                                                    const float* __restrict__ b,
                                                    float* __restrict__ xout) {
    int wave = (blockIdx.x * 256 + threadIdx.x) >> 6;
    int f = threadIdx.x & 63;
    if (wave >= N_NODES) return;
    int i = wave;
    float di = dinv[i];
    int e0 = row_start[i], e1 = row_end[i];
    float acc = 0.0f;
    int e = e0;
    for (; e + 3 < e1; e += 4) {               // 4-way ILP: overlap gathers
        int s0 = csr[e], s1 = csr[e + 1], s2 = csr[e + 2], s3 = csr[e + 3];
        float w0 = dinv[s0], w1 = dinv[s1], w2 = dinv[s2], w3 = dinv[s3];
        acc += h[(long long)s0 * H1 + f] * w0;
        acc += h[(long long)s1 * H1 + f] * w1;
        acc += h[(long long)s2 * H1 + f] * w2;
        acc += h[(long long)s3 * H1 + f] * w3;
    }
    for (; e < e1; ++e) {
        int s = csr[e];
        acc += h[(long long)s * H1 + f] * dinv[s];
    }
    acc *= di;
    float v = acc + h[(long long)i * H1 + f] * di * di + b[f];
    xout[(long long)i * H1 + f] = fmaxf(v, 0.0f);
}

// ---------------------------------------------------------------- pull aggregation, F=32: one wave per node, 2 edges/iter
__global__ __launch_bounds__(256) void pull2_kernel(const float* __restrict__ h,
                                                    const int* __restrict__ csr,
                                                    const int* __restrict__ row_start,
                                                    const int* __restrict__ row_end,
                                                    const float* __restrict__ dinv,
                                                    const float* __restrict__ b,
                                                    float* __restrict__ xout) {
    int wave = (blockIdx.x * 256 + threadIdx.x) >> 6;
    int lane = threadIdx.x & 63;
    int half = lane >> 5;
    int f = lane & 31;
    if (wave >= N_NODES) return;
    int i = wave;
    float di = dinv[i];
    int e0 = row_start[i], e1 = row_end[i];
    float acc = 0.0f;
    int e = e0 + half;
    for (; e + 2 < e1; e += 4) {               // each half: 2 edges/iter
        int s0 = csr[e], s1 = csr[e + 2];
        float w0 = dinv[s0], w1 = dinv[s1];
        acc += h[(long long)s0 * H2 + f] * w0;
        acc += h[(long long)s1 * H2 + f] * w1;
    }
    for (; e < e1; e += 2) {
        int s = csr[e];
        acc += h[(long long)s * H2 + f] * dinv[s];
    }
    acc += __shfl_xor(acc, 32);                // combine the two halves
    acc *= di;
    if (half == 0) {
        float v = acc + h[(long long)i * H2 + f] * di * di + b[f];
        xout[(long long)i * H2 + f] = fmaxf(v, 0.0f);
    }
}

// ---------------------------------------------------------------- classifier + log_softmax
__global__ __launch_bounds__(256) void final_kernel(const float* __restrict__ X2,
                                                    const float* __restrict__ Wc,
                                                    const float* __restrict__ bc,
                                                    float* __restrict__ out) {
    __shared__ float Ws[H2 * NCLS];   // 320 floats > 256 threads: loop
    __shared__ float bs[NCLS];
    for (int idx = threadIdx.x; idx < H2 * NCLS; idx += 256) Ws[idx] = Wc[idx];
    if (threadIdx.x < NCLS) bs[threadIdx.x] = bc[threadIdx.x];
    __syncthreads();
    int i = blockIdx.x * blockDim.x + threadIdx.x;
    if (i >= N_NODES) return;
    float x[H2];
    #pragma unroll
    for (int k = 0; k < H2; ++k) x[k] = X2[(long long)i * H2 + k];
    float lg[NCLS];
    #pragma unroll
    for (int c = 0; c < NCLS; ++c) {
        float acc = bs[c];
        #pragma unroll
        for (int k = 0; k < H2; ++k) acc += x[k] * Ws[k * NCLS + c];
        lg[c] = acc;
    }
    float m = lg[0];
    #pragma unroll
    for (int c = 1; c < NCLS; ++c) m = fmaxf(m, lg[c]);
    float s = 0.0f;
    #pragma unroll
    for (int c = 0; c < NCLS; ++c) s += expf(lg[c] - m);
    float lse = m + logf(s);
    #pragma unroll
    for (int c = 0; c < NCLS; ++c) out[(long long)i * NCLS + c] = lg[c] - lse;
}

// ----------------------------------------------------------------
extern "C" void kernel_launch(void* const* d_in, const int* in_sizes, int n_in,
                              void* d_out, int out_size, void* d_ws, size_t ws_size,
                              hipStream_t stream) {
    const float* feature = (const float*)d_in[0];
    const int*   eidx    = (const int*)d_in[1];
    const float* W1      = (const float*)d_in[2];
    const float* b1      = (const float*)d_in[3];
    const float* W2      = (const float*)d_in[4];
    const float* b2      = (const float*)d_in[5];
    const float* Wc      = (const float*)d_in[6];
    const float* bc      = (const float*)d_in[7];
    float* out = (float*)d_out;

    const int E = in_sizes[1] / 2;
    const int* src = eidx;
    const int* dst = eidx + E;

    // workspace layout:
    //   dinv        [N] float
    //   deg_cursor  [N] int   (degree -> row_start copy -> scatter cursor -> row_end)
    //   row_start   [N] int
    //   counter     [64] uint (only [0] used)
    //   csr         [E] int
    //   h1          [N*64] float   (after pull1: first half = h2, second half = x2)
    //   x1          [N*64] float
    float*        ws         = (float*)d_ws;
    float*        dinv       = ws;
    int*          deg_cursor = (int*)(dinv + N_NODES);
    int*          row_start  = deg_cursor + N_NODES;
    unsigned int* counter    = (unsigned int*)(row_start + N_NODES);
    int*          csr        = (int*)(counter + 64);
    float*        h1         = (float*)(csr + E);
    float*        x1         = h1 + (size_t)N_NODES * H1;
    float*        h2         = h1;                               // overlay: h1 dead after pull1
    float*        x2         = h1 + (size_t)N_NODES * H2;

    // zero degree histogram + counter (contiguous-ish: two small memsets)
    hipMemsetAsync(deg_cursor, 0, (size_t)N_NODES * sizeof(int), stream);
    hipMemsetAsync(counter, 0, 64 * sizeof(unsigned int), stream);

    // CSR build
    deg_count_kernel<<<(E + 255) / 256, 256, 0, stream>>>(dst, E, deg_cursor);
    dinv_kernel<<<(N_NODES + 255) / 256, 256, 0, stream>>>(deg_cursor, dinv, N_NODES);
    rowstart_kernel<<<(N_NODES + 255) / 256, 256, 0, stream>>>(deg_cursor, row_start, counter);
    scatter_kernel<<<(E + 255) / 256, 256, 0, stream>>>(src, dst, E, deg_cursor, csr);
    // after scatter: deg_cursor[i] == row_end[i]

    // layer 1
    gemm1_kernel<<<(N_NODES + 3) / 4, 256, 0, stream>>>(feature, W1, h1);
    {
        unsigned int grid = (unsigned int)(((size_t)N_NODES * H1 + 255) / 256);
        pull1_kernel<<<grid, 256, 0, stream>>>(h1, csr, row_start, deg_cursor, dinv, b1, x1);
    }

    // layer 2 (h1 region reused for h2/x2)
    gemm2_kernel<<<(N_NODES + 7) / 8, 256, 0, stream>>>(x1, W2, h2);
    {
        unsigned int grid = (unsigned int)((N_NODES * 64 + 255) / 256);
        pull2_kernel<<<grid, 256, 0, stream>>>(h2, csr, row_start, deg_cursor, dinv, b2, x2);
    }

    // classifier + log_softmax
    final_kernel<<<(N_NODES + 255) / 256, 256, 0, stream>>>(x2, Wc, bc, out);
}

// Round 4
// 677.894 us; speedup vs baseline: 2.0994x; 1.2890x over previous
//
#include <hip/hip_runtime.h>

#define N_NODES 100000
#define F_IN 128
#define H1 64
#define H2 32
#define NCLS 10

#define BS_N 256                                   // nodes per bucket
#define NB ((N_NODES + BS_N - 1) / BS_N)           // 391 buckets
#define CAP 9216                                   // slots/bucket: mean 8184, +11 sigma

// ---------------------------------------------------------------- pass 1: bin edges by dst bucket
// packed entry = (src << 8) | dst_local   (src < 2^17, dst_local < 256 -> 25 bits)
__global__ __launch_bounds__(256) void bin_kernel(const int* __restrict__ src,
                                                  const int* __restrict__ dst, int E,
                                                  unsigned int* __restrict__ bcur,
                                                  unsigned int* __restrict__ tmp) {
    int e = blockIdx.x * 256 + threadIdx.x;
    if (e < E) {
        int d = dst[e];
        int b = d >> 8;
        unsigned int pos = atomicAdd(&bcur[b * 16], 1u);   // 64B-padded cursors: 391 hot lines
        if (pos < CAP)
            tmp[(size_t)b * CAP + pos] =
                ((unsigned int)src[e] << 8) | (unsigned int)(d & 255);
    }
}

// ---------------------------------------------------------------- pass 2: per-bucket local CSR build
// one workgroup per bucket; LDS histogram + scan + scatter; rewrites bucket region in place
__global__ __launch_bounds__(256) void build_kernel(const unsigned int* __restrict__ bcur,
                                                    unsigned int* __restrict__ tmp_csr,
                                                    float* __restrict__ dinv,
                                                    int* __restrict__ row_start,
                                                    int* __restrict__ row_end) {
    __shared__ unsigned int stage[CAP];   // 36 KB
    __shared__ int degl[BS_N];
    __shared__ int rs_l[BS_N];
    __shared__ int curl[BS_N];
    __shared__ int wtot[4];
    int b = blockIdx.x;
    int tid = threadIdx.x;
    int c = (int)bcur[b * 16];
    if (c > CAP) c = CAP;
    for (int i = tid; i < c; i += 256) stage[i] = tmp_csr[(size_t)b * CAP + i];
    degl[tid] = 0;
    __syncthreads();
    for (int i = tid; i < c; i += 256) atomicAdd(&degl[stage[i] & 255], 1);
    __syncthreads();
    // exclusive scan over 256 degrees: wave inclusive scans + wave-total combine
    int lane = tid & 63, w = tid >> 6;
    int d = degl[tid];
    int x = d;
    #pragma unroll
    for (int off = 1; off < 64; off <<= 1) {
        int y = __shfl_up(x, off);
        if (lane >= off) x += y;
    }
    if (lane == 63) wtot[w] = x;
    __syncthreads();
    int base = 0;
    #pragma unroll
    for (int k = 0; k < 4; ++k) if (k < w) base += wtot[k];
    rs_l[tid] = base + x - d;          // exclusive prefix
    curl[tid] = 0;
    __syncthreads();
    // scatter: single-owner contiguous region -> full-line writes, no cross-XCD bounce
    for (int i = tid; i < c; i += 256) {
        unsigned int en = stage[i];
        int dl = en & 255;
        int p = atomicAdd(&curl[dl], 1);
        tmp_csr[(size_t)b * CAP + rs_l[dl] + p] = en >> 8;
    }
    int node = b * BS_N + tid;
    if (node < N_NODES) {
        int deg = degl[tid];
        dinv[node] = rsqrtf((float)deg + 1.0f);
        row_start[node] = b * CAP + rs_l[tid];
        row_end[node] = b * CAP + rs_l[tid] + deg;
    }
}

// ---------------------------------------------------------------- GEMM 1: [N,128] @ [128,64], scaled by dinv[row]
__global__ __launch_bounds__(256) void gemm1_kernel(const float* __restrict__ X,
                                                    const float* __restrict__ W,
                                                    const float* __restrict__ dinv,
                                                    float* __restrict__ H) {
    __shared__ float Ws[F_IN * H1];   // 32 KB
    __shared__ float Xs[4][F_IN];     // 2 KB
    int r0 = blockIdx.x * 4;
    for (int idx = threadIdx.x; idx < F_IN * H1; idx += 256) Ws[idx] = W[idx];
    for (int idx = threadIdx.x; idx < 4 * F_IN; idx += 256) {
        int r = idx / F_IN, k = idx - r * F_IN;
        int row = r0 + r;
        Xs[r][k] = (row < N_NODES) ? X[(long long)row * F_IN + k] : 0.0f;
    }
    __syncthreads();
    int col = threadIdx.x & 63;
    int r = threadIdx.x >> 6;
    int row = r0 + r;
    if (row < N_NODES) {
        float acc = 0.0f;
        #pragma unroll 8
        for (int k = 0; k < F_IN; ++k) acc += Xs[r][k] * Ws[k * H1 + col];
        H[(long long)row * H1 + col] = acc * dinv[row];   // h_pre = h * dinv
    }
}

// ---------------------------------------------------------------- GEMM 2: [N,64] @ [64,32], scaled by dinv[row]
__global__ __launch_bounds__(256) void gemm2_kernel(const float* __restrict__ X,
                                                    const float* __restrict__ W,
                                                    const float* __restrict__ dinv,
                                                    float* __restrict__ H) {
    __shared__ float Ws[H1 * H2];    // 8 KB
    __shared__ float Xs[8][H1];      // 2 KB
    int r0 = blockIdx.x * 8;
    for (int idx = threadIdx.x; idx < H1 * H2; idx += 256) Ws[idx] = W[idx];
    for (int idx = threadIdx.x; idx < 8 * H1; idx += 256) {
        int r = idx / H1, k = idx - r * H1;
        int row = r0 + r;
        Xs[r][k] = (row < N_NODES) ? X[(long long)row * H1 + k] : 0.0f;
    }
    __syncthreads();
    int col = threadIdx.x & 31;
    int r = threadIdx.x >> 5;
    int row = r0 + r;
    if (row < N_NODES) {
        float acc = 0.0f;
        #pragma unroll
        for (int k = 0; k < H1; ++k) acc += Xs[r][k] * Ws[k * H2 + col];
        H[(long long)row * H2 + col] = acc * dinv[row];   // h_pre = h * dinv
    }
}

// ---------------------------------------------------------------- pull aggregation, F=64: one wave per node
// xout[i] = relu( dinv[i] * (sum_s hpre[s] + hpre[i]) + b )
__global__ __launch_bounds__(256) void pull1_kernel(const float* __restrict__ h,
                                                    const unsigned int* __restrict__ csr,
                                                    const int* __restrict__ row_start,
                                                    const int* __restrict__ row_end,
                                                    const float* __restrict__ dinv,
                                                    const float* __restrict__ b,
                                                    float* __restrict__ xout) {
    int wave = (blockIdx.x * 256 + threadIdx.x) >> 6;
    int f = threadIdx.x & 63;
    if (wave >= N_NODES) return;
    int i = wave;
    int e0 = row_start[i], e1 = row_end[i];
    float acc = h[(long long)i * H1 + f];   // self loop
    int e = e0;
    for (; e + 3 < e1; e += 4) {            // 4-way ILP
        int s0 = csr[e], s1 = csr[e + 1], s2 = csr[e + 2], s3 = csr[e + 3];
        acc += h[(long long)s0 * H1 + f];
        acc += h[(long long)s1 * H1 + f];
        acc += h[(long long)s2 * H1 + f];
        acc += h[(long long)s3 * H1 + f];
    }
    for (; e < e1; ++e) acc += h[(long long)csr[e] * H1 + f];
    float v = dinv[i] * acc + b[f];
    xout[(long long)i * H1 + f] = fmaxf(v, 0.0f);
}

// ---------------------------------------------------------------- pull aggregation, F=32: one wave per node, 2 edges/iter
__global__ __launch_bounds__(256) void pull2_kernel(const float* __restrict__ h,
                                                    const unsigned int* __restrict__ csr,
                                                    const int* __restrict__ row_start,
                                                    const int* __restrict__ row_end,
                                                    const float* __restrict__ dinv,
                                                    const float* __restrict__ b,
                                                    float* __restrict__ xout) {
    int wave = (blockIdx.x * 256 + threadIdx.x) >> 6;
    int lane = threadIdx.x & 63;
    int half = lane >> 5;
    int f = lane & 31;
    if (wave >= N_NODES) return;
    int i = wave;
    int e0 = row_start[i], e1 = row_end[i];
    float acc = 0.0f;
    int e = e0 + half;
    for (; e + 2 < e1; e += 4) {
        int s0 = csr[e], s1 = csr[e + 2];
        acc += h[(long long)s0 * H2 + f];
        acc += h[(long long)s1 * H2 + f];
    }
    for (; e < e1; e += 2) acc += h[(long long)csr[e] * H2 + f];
    acc += __shfl_xor(acc, 32);
    if (half == 0) {
        float v = dinv[i] * (acc + h[(long long)i * H2 + f]) + b[f];
        xout[(long long)i * H2 + f] = fmaxf(v, 0.0f);
    }
}

// ---------------------------------------------------------------- classifier + log_softmax
__global__ __launch_bounds__(256) void final_kernel(const float* __restrict__ X2,
                                                    const float* __restrict__ Wc,
                                                    const float* __restrict__ bc,
                                                    float* __restrict__ out) {
    __shared__ float Ws[H2 * NCLS];   // 320 floats > 256 threads: loop
    __shared__ float bs[NCLS];
    for (int idx = threadIdx.x; idx < H2 * NCLS; idx += 256) Ws[idx] = Wc[idx];
    if (threadIdx.x < NCLS) bs[threadIdx.x] = bc[threadIdx.x];
    __syncthreads();
    int i = blockIdx.x * blockDim.x + threadIdx.x;
    if (i >= N_NODES) return;
    float x[H2];
    #pragma unroll
    for (int k = 0; k < H2; ++k) x[k] = X2[(long long)i * H2 + k];
    float lg[NCLS];
    #pragma unroll
    for (int c = 0; c < NCLS; ++c) {
        float acc = bs[c];
        #pragma unroll
        for (int k = 0; k < H2; ++k) acc += x[k] * Ws[k * NCLS + c];
        lg[c] = acc;
    }
    float m = lg[0];
    #pragma unroll
    for (int c = 1; c < NCLS; ++c) m = fmaxf(m, lg[c]);
    float s = 0.0f;
    #pragma unroll
    for (int c = 0; c < NCLS; ++c) s += expf(lg[c] - m);
    float lse = m + logf(s);
    #pragma unroll
    for (int c = 0; c < NCLS; ++c) out[(long long)i * NCLS + c] = lg[c] - lse;
}

// ----------------------------------------------------------------
extern "C" void kernel_launch(void* const* d_in, const int* in_sizes, int n_in,
                              void* d_out, int out_size, void* d_ws, size_t ws_size,
                              hipStream_t stream) {
    const float* feature = (const float*)d_in[0];
    const int*   eidx    = (const int*)d_in[1];
    const float* W1      = (const float*)d_in[2];
    const float* b1      = (const float*)d_in[3];
    const float* W2      = (const float*)d_in[4];
    const float* b2      = (const float*)d_in[5];
    const float* Wc      = (const float*)d_in[6];
    const float* bc      = (const float*)d_in[7];
    float* out = (float*)d_out;

    const int E = in_sizes[1] / 2;
    const int* src = eidx;
    const int* dst = eidx + E;

    // workspace layout (4B units):
    //   dinv      [N] float
    //   row_start [N] int
    //   row_end   [N] int
    //   bcur      [NB*16] uint (64B-padded bucket cursors)
    //   tmp_csr   [NB*CAP] uint (packed edges, then CSR src indices in place)
    //   h1        [N*64] float (scaled; overlays h2 [N*32] then x2 [N*32] for layer 2)
    //   x1        [N*64] float
    float*        ws        = (float*)d_ws;
    float*        dinv      = ws;
    int*          row_start = (int*)(dinv + N_NODES);
    int*          row_end   = row_start + N_NODES;
    unsigned int* bcur      = (unsigned int*)(row_end + N_NODES);
    unsigned int* tmp_csr   = bcur + (size_t)NB * 16;
    float*        h1        = (float*)(tmp_csr + (size_t)NB * CAP);
    float*        x1        = h1 + (size_t)N_NODES * H1;
    float*        h2        = h1;                            // overlay: h1 dead after pull1
    float*        x2        = h1 + (size_t)N_NODES * H2;

    // CSR build (replaces deg_count + scan + scatter)
    hipMemsetAsync(bcur, 0, (size_t)NB * 16 * sizeof(unsigned int), stream);
    bin_kernel<<<(E + 255) / 256, 256, 0, stream>>>(src, dst, E, bcur, tmp_csr);
    build_kernel<<<NB, 256, 0, stream>>>(bcur, tmp_csr, dinv, row_start, row_end);

    // layer 1
    gemm1_kernel<<<(N_NODES + 3) / 4, 256, 0, stream>>>(feature, W1, dinv, h1);
    {
        unsigned int grid = (unsigned int)(((size_t)N_NODES * H1 + 255) / 256);
        pull1_kernel<<<grid, 256, 0, stream>>>(h1, tmp_csr, row_start, row_end, dinv, b1, x1);
    }

    // layer 2 (h1 region reused for h2/x2)
    gemm2_kernel<<<(N_NODES + 7) / 8, 256, 0, stream>>>(x1, W2, dinv, h2);
    {
        unsigned int grid = (unsigned int)((N_NODES * 64 + 255) / 256);
        pull2_kernel<<<grid, 256, 0, stream>>>(h2, tmp_csr, row_start, row_end, dinv, b2, x2);
    }

    // classifier + log_softmax
    final_kernel<<<(N_NODES + 255) / 256, 256, 0, stream>>>(x2, Wc, bc, out);
}

// Round 5
// 671.863 us; speedup vs baseline: 2.1182x; 1.0090x over previous
//
#include <hip/hip_runtime.h>

#define N_NODES 100000
#define F_IN 128
#define H1 64
#define H2 32
#define NCLS 10

#define BS_N 256                                   // nodes per bucket
#define NB ((N_NODES + BS_N - 1) / BS_N)           // 391 buckets
#define NSUB 8                                     // per-XCD sub-regions
#define SCAP 4096                                  // slots per (bucket, xcd): mean 1023
#define STCAP 9216                                 // LDS stage capacity: mean 8184, +11 sigma
#define OCAP (2 * 1024 * 1024)                     // overflow edge-id capacity (worst-case proof)

// HW_REG_XCC_ID = 20, bits [3:0]  -> getreg imm = ((4-1)<<11) | (0<<6) | 20
#define XCC_GETREG_IMM 6164

// ---------------------------------------------------------------- pass 1: bin edges by (dst bucket, XCD)
// packed entry = (src << 8) | dst_local
__global__ __launch_bounds__(256) void bin_kernel(const int* __restrict__ src,
                                                  const int* __restrict__ dst, int E,
                                                  unsigned int* __restrict__ scur,
                                                  unsigned int* __restrict__ tmp,
                                                  unsigned int* __restrict__ ov_cnt,
                                                  unsigned int* __restrict__ ov) {
    int e = blockIdx.x * 256 + threadIdx.x;
    if (e >= E) return;
    int xcc = __builtin_amdgcn_s_getreg(XCC_GETREG_IMM) & (NSUB - 1);  // wave-uniform
    int d = dst[e];
    int b = d >> 8;
    // cursor per (bucket,xcd), each on its own 64B line; only this XCD touches it
    unsigned int pos = atomicAdd(&scur[(b * NSUB + xcc) * 16], 1u);
    if (pos < SCAP) {
        tmp[((size_t)b * NSUB + xcc) * SCAP + pos] =
            ((unsigned int)src[e] << 8) | (unsigned int)(d & 255);
    } else {
        unsigned int op = atomicAdd(ov_cnt, 1u);   // essentially never taken
        if (op < OCAP) ov[op] = (unsigned int)e;
    }
}

// ---------------------------------------------------------------- pass 2: per-bucket local CSR build
__global__ __launch_bounds__(256) void build_kernel(const unsigned int* __restrict__ scur,
                                                    unsigned int* __restrict__ tmp,
                                                    const unsigned int* __restrict__ ov_cnt,
                                                    const unsigned int* __restrict__ ov,
                                                    const int* __restrict__ src,
                                                    const int* __restrict__ dst,
                                                    float* __restrict__ dinv,
                                                    int* __restrict__ row_start,
                                                    int* __restrict__ row_end) {
    __shared__ unsigned int stage[STCAP];   // 36 KB
    __shared__ int degl[BS_N];
    __shared__ int rs_l[BS_N];
    __shared__ int curl[BS_N];
    __shared__ int wtot[4];
    __shared__ int stot;
    int b = blockIdx.x;
    int tid = threadIdx.x;

    // stage the 8 sub-lists, concatenated
    int base = 0;
    #pragma unroll
    for (int x = 0; x < NSUB; ++x) {
        int c = (int)scur[(b * NSUB + x) * 16];
        if (c > SCAP) c = SCAP;
        for (int i = tid; i < c; i += 256) {
            int p = base + i;
            if (p < STCAP) stage[p] = tmp[((size_t)b * NSUB + x) * SCAP + i];
        }
        base += c;
    }
    if (base > STCAP) base = STCAP;
    if (tid == 0) stot = base;
    degl[tid] = 0;
    __syncthreads();

    // overflow slow path (oc == 0 in all sane dispatches)
    unsigned int oc = *ov_cnt;
    if (oc) {
        if (oc > OCAP) oc = OCAP;
        for (unsigned int i = tid; i < oc; i += 256) {
            int e = (int)ov[i];
            int d = dst[e];
            if ((d >> 8) == b) {
                int p = atomicAdd(&stot, 1);
                if (p < STCAP)
                    stage[p] = ((unsigned int)src[e] << 8) | (unsigned int)(d & 255);
            }
        }
        __syncthreads();
    }
    int c = stot;
    if (c > STCAP) c = STCAP;

    // degree histogram (LDS atomics)
    for (int i = tid; i < c; i += 256) atomicAdd(&degl[stage[i] & 255], 1);
    __syncthreads();

    // exclusive scan over 256 degrees
    int lane = tid & 63, w = tid >> 6;
    int d = degl[tid];
    int x = d;
    #pragma unroll
    for (int off = 1; off < 64; off <<= 1) {
        int y = __shfl_up(x, off);
        if (lane >= off) x += y;
    }
    if (lane == 63) wtot[w] = x;
    __syncthreads();
    int pbase = 0;
    #pragma unroll
    for (int k = 0; k < 4; ++k) if (k < w) pbase += wtot[k];
    rs_l[tid] = pbase + x - d;
    curl[tid] = 0;
    __syncthreads();

    // scatter into dense CSR at the bucket base (single-owner full-line writes)
    size_t gbase = (size_t)b * NSUB * SCAP;
    for (int i = tid; i < c; i += 256) {
        unsigned int en = stage[i];
        int dl = en & 255;
        int p = atomicAdd(&curl[dl], 1);
        tmp[gbase + rs_l[dl] + p] = en >> 8;
    }
    int node = b * BS_N + tid;
    if (node < N_NODES) {
        int deg = degl[tid];
        dinv[node] = rsqrtf((float)deg + 1.0f);
        row_start[node] = (int)gbase + rs_l[tid];
        row_end[node] = (int)gbase + rs_l[tid] + deg;
    }
}

// ---------------------------------------------------------------- GEMM 1: [N,128] @ [128,64], scaled by dinv[row]
__global__ __launch_bounds__(256) void gemm1_kernel(const float* __restrict__ X,
                                                    const float* __restrict__ W,
                                                    const float* __restrict__ dinv,
                                                    float* __restrict__ H) {
    __shared__ float Ws[F_IN * H1];   // 32 KB
    __shared__ float Xs[4][F_IN];     // 2 KB
    int r0 = blockIdx.x * 4;
    for (int idx = threadIdx.x; idx < F_IN * H1; idx += 256) Ws[idx] = W[idx];
    for (int idx = threadIdx.x; idx < 4 * F_IN; idx += 256) {
        int r = idx / F_IN, k = idx - r * F_IN;
        int row = r0 + r;
        Xs[r][k] = (row < N_NODES) ? X[(long long)row * F_IN + k] : 0.0f;
    }
    __syncthreads();
    int col = threadIdx.x & 63;
    int r = threadIdx.x >> 6;
    int row = r0 + r;
    if (row < N_NODES) {
        float acc = 0.0f;
        #pragma unroll 8
        for (int k = 0; k < F_IN; ++k) acc += Xs[r][k] * Ws[k * H1 + col];
        H[(long long)row * H1 + col] = acc * dinv[row];   // h_pre = h * dinv
    }
}

// ---------------------------------------------------------------- GEMM 2: [N,64] @ [64,32], scaled by dinv[row]
__global__ __launch_bounds__(256) void gemm2_kernel(const float* __restrict__ X,
                                                    const float* __restrict__ W,
                                                    const float* __restrict__ dinv,
                                                    float* __restrict__ H) {
    __shared__ float Ws[H1 * H2];    // 8 KB
    __shared__ float Xs[8][H1];      // 2 KB
    int r0 = blockIdx.x * 8;
    for (int idx = threadIdx.x; idx < H1 * H2; idx += 256) Ws[idx] = W[idx];
    for (int idx = threadIdx.x; idx < 8 * H1; idx += 256) {
        int r = idx / H1, k = idx - r * H1;
        int row = r0 + r;
        Xs[r][k] = (row < N_NODES) ? X[(long long)row * H1 + k] : 0.0f;
    }
    __syncthreads();
    int col = threadIdx.x & 31;
    int r = threadIdx.x >> 5;
    int row = r0 + r;
    if (row < N_NODES) {
        float acc = 0.0f;
        #pragma unroll
        for (int k = 0; k < H1; ++k) acc += Xs[r][k] * Ws[k * H2 + col];
        H[(long long)row * H2 + col] = acc * dinv[row];   // h_pre = h * dinv
    }
}

// ---------------------------------------------------------------- pull aggregation, F=64: one wave per node
__global__ __launch_bounds__(256) void pull1_kernel(const float* __restrict__ h,
                                                    const unsigned int* __restrict__ csr,
                                                    const int* __restrict__ row_start,
                                                    const int* __restrict__ row_end,
                                                    const float* __restrict__ dinv,
                                                    const float* __restrict__ b,
                                                    float* __restrict__ xout) {
    int wave = (blockIdx.x * 256 + threadIdx.x) >> 6;
    int f = threadIdx.x & 63;
    if (wave >= N_NODES) return;
    int i = wave;
    int e0 = row_start[i], e1 = row_end[i];
    float acc = h[(long long)i * H1 + f];   // self loop
    int e = e0;
    for (; e + 3 < e1; e += 4) {            // 4-way ILP
        int s0 = csr[e], s1 = csr[e + 1], s2 = csr[e + 2], s3 = csr[e + 3];
        acc += h[(long long)s0 * H1 + f];
        acc += h[(long long)s1 * H1 + f];
        acc += h[(long long)s2 * H1 + f];
        acc += h[(long long)s3 * H1 + f];
    }
    for (; e < e1; ++e) acc += h[(long long)csr[e] * H1 + f];
    float v = dinv[i] * acc + b[f];
    xout[(long long)i * H1 + f] = fmaxf(v, 0.0f);
}

// ---------------------------------------------------------------- pull aggregation, F=32: one wave per node, 2 edges/iter
__global__ __launch_bounds__(256) void pull2_kernel(const float* __restrict__ h,
                                                    const unsigned int* __restrict__ csr,
                                                    const int* __restrict__ row_start,
                                                    const int* __restrict__ row_end,
                                                    const float* __restrict__ dinv,
                                                    const float* __restrict__ b,
                                                    float* __restrict__ xout) {
    int wave = (blockIdx.x * 256 + threadIdx.x) >> 6;
    int lane = threadIdx.x & 63;
    int half = lane >> 5;
    int f = lane & 31;
    if (wave >= N_NODES) return;
    int i = wave;
    int e0 = row_start[i], e1 = row_end[i];
    float acc = 0.0f;
    int e = e0 + half;
    for (; e + 2 < e1; e += 4) {
        int s0 = csr[e], s1 = csr[e + 2];
        acc += h[(long long)s0 * H2 + f];
        acc += h[(long long)s1 * H2 + f];
    }
    for (; e < e1; e += 2) acc += h[(long long)csr[e] * H2 + f];
    acc += __shfl_xor(acc, 32);
    if (half == 0) {
        float v = dinv[i] * (acc + h[(long long)i * H2 + f]) + b[f];
        xout[(long long)i * H2 + f] = fmaxf(v, 0.0f);
    }
}

// ---------------------------------------------------------------- classifier + log_softmax
__global__ __launch_bounds__(256) void final_kernel(const float* __restrict__ X2,
                                                    const float* __restrict__ Wc,
                                                    const float* __restrict__ bc,
                                                    float* __restrict__ out) {
    __shared__ float Ws[H2 * NCLS];   // 320 floats > 256 threads: loop
    __shared__ float bs[NCLS];
    for (int idx = threadIdx.x; idx < H2 * NCLS; idx += 256) Ws[idx] = Wc[idx];
    if (threadIdx.x < NCLS) bs[threadIdx.x] = bc[threadIdx.x];
    __syncthreads();
    int i = blockIdx.x * blockDim.x + threadIdx.x;
    if (i >= N_NODES) return;
    float x[H2];
    #pragma unroll
    for (int k = 0; k < H2; ++k) x[k] = X2[(long long)i * H2 + k];
    float lg[NCLS];
    #pragma unroll
    for (int c = 0; c < NCLS; ++c) {
        float acc = bs[c];
        #pragma unroll
        for (int k = 0; k < H2; ++k) acc += x[k] * Ws[k * NCLS + c];
        lg[c] = acc;
    }
    float m = lg[0];
    #pragma unroll
    for (int c = 1; c < NCLS; ++c) m = fmaxf(m, lg[c]);
    float s = 0.0f;
    #pragma unroll
    for (int c = 0; c < NCLS; ++c) s += expf(lg[c] - m);
    float lse = m + logf(s);
    #pragma unroll
    for (int c = 0; c < NCLS; ++c) out[(long long)i * NCLS + c] = lg[c] - lse;
}

// ----------------------------------------------------------------
extern "C" void kernel_launch(void* const* d_in, const int* in_sizes, int n_in,
                              void* d_out, int out_size, void* d_ws, size_t ws_size,
                              hipStream_t stream) {
    const float* feature = (const float*)d_in[0];
    const int*   eidx    = (const int*)d_in[1];
    const float* W1      = (const float*)d_in[2];
    const float* b1      = (const float*)d_in[3];
    const float* W2      = (const float*)d_in[4];
    const float* b2      = (const float*)d_in[5];
    const float* Wc      = (const float*)d_in[6];
    const float* bc      = (const float*)d_in[7];
    float* out = (float*)d_out;

    const int E = in_sizes[1] / 2;
    const int* src = eidx;
    const int* dst = eidx + E;

    // workspace layout (4B units):
    //   dinv      [N] float
    //   row_start [N] int
    //   row_end   [N] int
    //   scur      [NB*NSUB*16] uint (64B-padded per-(bucket,xcd) cursors)  ~200 KB
    //   ov_cnt    [16] uint
    //   ov        [OCAP] uint (overflow edge ids)                          8 MB
    //   tmp_csr   [NB*NSUB*SCAP] uint (staged edges -> dense CSR in place) 51.2 MB
    //   h1        [N*64] float (overlays h2/x2 for layer 2)                25.6 MB
    //   x1        [N*64] float                                             25.6 MB
    float*        ws        = (float*)d_ws;
    float*        dinv      = ws;
    int*          row_start = (int*)(dinv + N_NODES);
    int*          row_end   = row_start + N_NODES;
    unsigned int* scur      = (unsigned int*)(row_end + N_NODES);
    unsigned int* ov_cnt    = scur + (size_t)NB * NSUB * 16;
    unsigned int* ov        = ov_cnt + 16;
    unsigned int* tmp_csr   = ov + OCAP;
    float*        h1        = (float*)(tmp_csr + (size_t)NB * NSUB * SCAP);
    float*        x1        = h1 + (size_t)N_NODES * H1;
    float*        h2        = h1;                            // overlay: h1 dead after pull1
    float*        x2        = h1 + (size_t)N_NODES * H2;

    // CSR build
    hipMemsetAsync(scur, 0, ((size_t)NB * NSUB * 16 + 16) * sizeof(unsigned int), stream);
    bin_kernel<<<(E + 255) / 256, 256, 0, stream>>>(src, dst, E, scur, tmp_csr, ov_cnt, ov);
    build_kernel<<<NB, 256, 0, stream>>>(scur, tmp_csr, ov_cnt, ov, src, dst,
                                         dinv, row_start, row_end);

    // layer 1
    gemm1_kernel<<<(N_NODES + 3) / 4, 256, 0, stream>>>(feature, W1, dinv, h1);
    {
        unsigned int grid = (unsigned int)(((size_t)N_NODES * H1 + 255) / 256);
        pull1_kernel<<<grid, 256, 0, stream>>>(h1, tmp_csr, row_start, row_end, dinv, b1, x1);
    }

    // layer 2 (h1 region reused for h2/x2)
    gemm2_kernel<<<(N_NODES + 7) / 8, 256, 0, stream>>>(x1, W2, dinv, h2);
    {
        unsigned int grid = (unsigned int)((N_NODES * 64 + 255) / 256);
        pull2_kernel<<<grid, 256, 0, stream>>>(h2, tmp_csr, row_start, row_end, dinv, b2, x2);
    }

    // classifier + log_softmax
    final_kernel<<<(N_NODES + 255) / 256, 256, 0, stream>>>(x2, Wc, bc, out);
}

// Round 6
// 538.810 us; speedup vs baseline: 2.6413x; 1.2469x over previous
//
#include <hip/hip_runtime.h>

#define N_NODES 100000
#define F_IN 128
#define H1 64
#define H2 32
#define NCLS 10

#define BS_N 256                                   // nodes per bucket
#define NB ((N_NODES + BS_N - 1) / BS_N)           // 391 buckets
#define NSUB 8                                     // per-XCD sub-regions
#define SCAP 4096                                  // slots per (bucket, xcd): mean 1023
#define STCAP 9216                                 // LDS stage capacity: mean 8184, +11 sigma
#define OCAP (2 * 1024 * 1024)                     // overflow edge-id capacity (worst-case proof)

// HW_REG_XCC_ID = 20, bits [3:0]  -> getreg imm = ((4-1)<<11) | (0<<6) | 20
#define XCC_GETREG_IMM 6164

__device__ __forceinline__ unsigned short f2bf(float f) {   // RNE f32->bf16
    unsigned int u = __float_as_uint(f);
    return (unsigned short)((u + 0x7fffu + ((u >> 16) & 1u)) >> 16);
}
__device__ __forceinline__ float bf2f(unsigned short u) {
    return __uint_as_float((unsigned int)u << 16);
}

// ---------------------------------------------------------------- pass 1: bin edges by (dst bucket, XCD)
__global__ __launch_bounds__(256) void bin_kernel(const int* __restrict__ src,
                                                  const int* __restrict__ dst, int E,
                                                  unsigned int* __restrict__ scur,
                                                  unsigned int* __restrict__ tmp,
                                                  unsigned int* __restrict__ ov_cnt,
                                                  unsigned int* __restrict__ ov) {
    int e = blockIdx.x * 256 + threadIdx.x;
    if (e >= E) return;
    int xcc = __builtin_amdgcn_s_getreg(XCC_GETREG_IMM) & (NSUB - 1);  // wave-uniform
    int d = dst[e];
    int b = d >> 8;
    unsigned int pos = atomicAdd(&scur[(b * NSUB + xcc) * 16], 1u);
    if (pos < SCAP) {
        tmp[((size_t)b * NSUB + xcc) * SCAP + pos] =
            ((unsigned int)src[e] << 8) | (unsigned int)(d & 255);
    } else {
        unsigned int op = atomicAdd(ov_cnt, 1u);   // essentially never taken
        if (op < OCAP) ov[op] = (unsigned int)e;
    }
}

// ---------------------------------------------------------------- pass 2: per-bucket local CSR build
__global__ __launch_bounds__(256) void build_kernel(const unsigned int* __restrict__ scur,
                                                    unsigned int* __restrict__ tmp,
                                                    const unsigned int* __restrict__ ov_cnt,
                                                    const unsigned int* __restrict__ ov,
                                                    const int* __restrict__ src,
                                                    const int* __restrict__ dst,
                                                    float* __restrict__ dinv,
                                                    int* __restrict__ row_start,
                                                    int* __restrict__ row_end) {
    __shared__ unsigned int stage[STCAP];   // 36 KB
    __shared__ int degl[BS_N];
    __shared__ int rs_l[BS_N];
    __shared__ int curl[BS_N];
    __shared__ int wtot[4];
    __shared__ int stot;
    int b = blockIdx.x;
    int tid = threadIdx.x;

    int base = 0;
    #pragma unroll
    for (int x = 0; x < NSUB; ++x) {
        int c = (int)scur[(b * NSUB + x) * 16];
        if (c > SCAP) c = SCAP;
        for (int i = tid; i < c; i += 256) {
            int p = base + i;
            if (p < STCAP) stage[p] = tmp[((size_t)b * NSUB + x) * SCAP + i];
        }
        base += c;
    }
    if (base > STCAP) base = STCAP;
    if (tid == 0) stot = base;
    degl[tid] = 0;
    __syncthreads();

    unsigned int oc = *ov_cnt;          // overflow slow path (normally 0)
    if (oc) {
        if (oc > OCAP) oc = OCAP;
        for (unsigned int i = tid; i < oc; i += 256) {
            int e = (int)ov[i];
            int d = dst[e];
            if ((d >> 8) == b) {
                int p = atomicAdd(&stot, 1);
                if (p < STCAP)
                    stage[p] = ((unsigned int)src[e] << 8) | (unsigned int)(d & 255);
            }
        }
        __syncthreads();
    }
    int c = stot;
    if (c > STCAP) c = STCAP;

    for (int i = tid; i < c; i += 256) atomicAdd(&degl[stage[i] & 255], 1);
    __syncthreads();

    int lane = tid & 63, w = tid >> 6;
    int d = degl[tid];
    int x = d;
    #pragma unroll
    for (int off = 1; off < 64; off <<= 1) {
        int y = __shfl_up(x, off);
        if (lane >= off) x += y;
    }
    if (lane == 63) wtot[w] = x;
    __syncthreads();
    int pbase = 0;
    #pragma unroll
    for (int k = 0; k < 4; ++k) if (k < w) pbase += wtot[k];
    rs_l[tid] = pbase + x - d;
    curl[tid] = 0;
    __syncthreads();

    size_t gbase = (size_t)b * NSUB * SCAP;
    for (int i = tid; i < c; i += 256) {
        unsigned int en = stage[i];
        int dl = en & 255;
        int p = atomicAdd(&curl[dl], 1);
        tmp[gbase + rs_l[dl] + p] = en >> 8;
    }
    int node = b * BS_N + tid;
    if (node < N_NODES) {
        int deg = degl[tid];
        dinv[node] = rsqrtf((float)deg + 1.0f);
        row_start[node] = (int)gbase + rs_l[tid];
        row_end[node] = (int)gbase + rs_l[tid] + deg;
    }
}

// ---------------------------------------------------------------- GEMM 1: [N,128]@[128,64] -> bf16, scaled by dinv
// 64x64 tile, 256 threads, 4x4 accums; K staged in 2 halves; LDS ~49.4 KB
__global__ __launch_bounds__(256) void gemm1_kernel(const float* __restrict__ X,
                                                    const float* __restrict__ W,
                                                    const float* __restrict__ dinv,
                                                    unsigned short* __restrict__ H) {
    __shared__ float Xs[64][68];      // 17.4 KB, pad 68: 2-way-free bank pattern
    __shared__ float Ws[F_IN * H1];   // 32 KB
    int r0 = blockIdx.x * 64;
    const float4* W4 = (const float4*)W;
    float4* Ws4 = (float4*)Ws;
    for (int i = threadIdx.x; i < F_IN * H1 / 4; i += 256) Ws4[i] = W4[i];

    int tx = threadIdx.x & 15;        // col group: cols tx*4..+3
    int ty = threadIdx.x >> 4;        // row group: rows ty*4..+3
    float acc[4][4] = {};

    for (int kh = 0; kh < 2; ++kh) {
        __syncthreads();
        // stage X tile half: 64 rows x 64 k = 1024 float4
        for (int it = 0; it < 4; ++it) {
            int idx = threadIdx.x + it * 256;
            int r = idx >> 4, k4 = idx & 15;
            int row = r0 + r;
            float4 v = (row < N_NODES)
                ? ((const float4*)X)[(size_t)row * 32 + kh * 16 + k4]
                : make_float4(0.f, 0.f, 0.f, 0.f);
            *(float4*)&Xs[r][k4 * 4] = v;      // row stride 272 B: 16B-aligned
        }
        __syncthreads();
        #pragma unroll 8
        for (int k = 0; k < 64; ++k) {
            float4 wb = *(const float4*)&Ws[(kh * 64 + k) * H1 + tx * 4];
            float xa0 = Xs[ty * 4 + 0][k];
            float xa1 = Xs[ty * 4 + 1][k];
            float xa2 = Xs[ty * 4 + 2][k];
            float xa3 = Xs[ty * 4 + 3][k];
            acc[0][0] += xa0 * wb.x; acc[0][1] += xa0 * wb.y; acc[0][2] += xa0 * wb.z; acc[0][3] += xa0 * wb.w;
            acc[1][0] += xa1 * wb.x; acc[1][1] += xa1 * wb.y; acc[1][2] += xa1 * wb.z; acc[1][3] += xa1 * wb.w;
            acc[2][0] += xa2 * wb.x; acc[2][1] += xa2 * wb.y; acc[2][2] += xa2 * wb.z; acc[2][3] += xa2 * wb.w;
            acc[3][0] += xa3 * wb.x; acc[3][1] += xa3 * wb.y; acc[3][2] += xa3 * wb.z; acc[3][3] += xa3 * wb.w;
        }
    }
    #pragma unroll
    for (int i = 0; i < 4; ++i) {
        int row = r0 + ty * 4 + i;
        if (row < N_NODES) {
            float dv = dinv[row];
            unsigned int lo = (unsigned int)f2bf(acc[i][0] * dv) |
                              ((unsigned int)f2bf(acc[i][1] * dv) << 16);
            unsigned int hi = (unsigned int)f2bf(acc[i][2] * dv) |
                              ((unsigned int)f2bf(acc[i][3] * dv) << 16);
            *(uint2*)&H[(size_t)row * H1 + tx * 4] = make_uint2(lo, hi);
        }
    }
}

// ---------------------------------------------------------------- GEMM 2: [N,64]@[64,32] -> bf16, scaled by dinv
// 64x32 tile, 256 threads, 4x2 accums; LDS ~25.4 KB
__global__ __launch_bounds__(256) void gemm2_kernel(const float* __restrict__ X,
                                                    const float* __restrict__ W,
                                                    const float* __restrict__ dinv,
                                                    unsigned short* __restrict__ H) {
    __shared__ float Xs[64][68];     // 17.4 KB
    __shared__ float Ws[H1 * H2];    // 8 KB
    int r0 = blockIdx.x * 64;
    const float4* W4 = (const float4*)W;
    float4* Ws4 = (float4*)Ws;
    for (int i = threadIdx.x; i < H1 * H2 / 4; i += 256) Ws4[i] = W4[i];
    // stage X tile: 64 rows x 64 k = 1024 float4
    for (int it = 0; it < 4; ++it) {
        int idx = threadIdx.x + it * 256;
        int r = idx >> 4, k4 = idx & 15;
        int row = r0 + r;
        float4 v = (row < N_NODES)
            ? ((const float4*)X)[(size_t)row * 16 + k4]
            : make_float4(0.f, 0.f, 0.f, 0.f);
        *(float4*)&Xs[r][k4 * 4] = v;
    }
    __syncthreads();
    int tx = threadIdx.x & 15;       // col pair: cols tx*2..+1
    int ty = threadIdx.x >> 4;       // rows ty*4..+3
    float acc[4][2] = {};
    #pragma unroll 8
    for (int k = 0; k < 64; ++k) {
        float2 wb = *(const float2*)&Ws[k * H2 + tx * 2];
        float xa0 = Xs[ty * 4 + 0][k];
        float xa1 = Xs[ty * 4 + 1][k];
        float xa2 = Xs[ty * 4 + 2][k];
        float xa3 = Xs[ty * 4 + 3][k];
        acc[0][0] += xa0 * wb.x; acc[0][1] += xa0 * wb.y;
        acc[1][0] += xa1 * wb.x; acc[1][1] += xa1 * wb.y;
        acc[2][0] += xa2 * wb.x; acc[2][1] += xa2 * wb.y;
        acc[3][0] += xa3 * wb.x; acc[3][1] += xa3 * wb.y;
    }
    #pragma unroll
    for (int i = 0; i < 4; ++i) {
        int row = r0 + ty * 4 + i;
        if (row < N_NODES) {
            float dv = dinv[row];
            unsigned int v = (unsigned int)f2bf(acc[i][0] * dv) |
                             ((unsigned int)f2bf(acc[i][1] * dv) << 16);
            *(unsigned int*)&H[(size_t)row * H2 + tx * 2] = v;
        }
    }
}

// ---------------------------------------------------------------- pull aggregation, F=64 (bf16 gathers)
__global__ __launch_bounds__(256) void pull1_kernel(const unsigned short* __restrict__ h,
                                                    const unsigned int* __restrict__ csr,
                                                    const int* __restrict__ row_start,
                                                    const int* __restrict__ row_end,
                                                    const float* __restrict__ dinv,
                                                    const float* __restrict__ b,
                                                    float* __restrict__ xout) {
    int wave = (blockIdx.x * 256 + threadIdx.x) >> 6;
    int f = threadIdx.x & 63;
    if (wave >= N_NODES) return;
    int i = wave;
    int e0 = row_start[i], e1 = row_end[i];
    float acc = bf2f(h[(size_t)i * H1 + f]);   // self loop
    int e = e0;
    for (; e + 3 < e1; e += 4) {               // 4-way ILP
        int s0 = csr[e], s1 = csr[e + 1], s2 = csr[e + 2], s3 = csr[e + 3];
        acc += bf2f(h[(size_t)s0 * H1 + f]);
        acc += bf2f(h[(size_t)s1 * H1 + f]);
        acc += bf2f(h[(size_t)s2 * H1 + f]);
        acc += bf2f(h[(size_t)s3 * H1 + f]);
    }
    for (; e < e1; ++e) acc += bf2f(h[(size_t)csr[e] * H1 + f]);
    float v = dinv[i] * acc + b[f];
    xout[(size_t)i * H1 + f] = fmaxf(v, 0.0f);
}

// ---------------------------------------------------------------- pull aggregation, F=32 (bf16 gathers)
__global__ __launch_bounds__(256) void pull2_kernel(const unsigned short* __restrict__ h,
                                                    const unsigned int* __restrict__ csr,
                                                    const int* __restrict__ row_start,
                                                    const int* __restrict__ row_end,
                                                    const float* __restrict__ dinv,
                                                    const float* __restrict__ b,
                                                    float* __restrict__ xout) {
    int wave = (blockIdx.x * 256 + threadIdx.x) >> 6;
    int lane = threadIdx.x & 63;
    int half = lane >> 5;
    int f = lane & 31;
    if (wave >= N_NODES) return;
    int i = wave;
    int e0 = row_start[i], e1 = row_end[i];
    float acc = 0.0f;
    int e = e0 + half;
    for (; e + 2 < e1; e += 4) {
        int s0 = csr[e], s1 = csr[e + 2];
        acc += bf2f(h[(size_t)s0 * H2 + f]);
        acc += bf2f(h[(size_t)s1 * H2 + f]);
    }
    for (; e < e1; e += 2) acc += bf2f(h[(size_t)csr[e] * H2 + f]);
    acc += __shfl_xor(acc, 32);
    if (half == 0) {
        float v = dinv[i] * (acc + bf2f(h[(size_t)i * H2 + f])) + b[f];
        xout[(size_t)i * H2 + f] = fmaxf(v, 0.0f);
    }
}

// ---------------------------------------------------------------- classifier + log_softmax
__global__ __launch_bounds__(256) void final_kernel(const float* __restrict__ X2,
                                                    const float* __restrict__ Wc,
                                                    const float* __restrict__ bc,
                                                    float* __restrict__ out) {
    __shared__ float Ws[H2 * NCLS];   // 320 floats > 256 threads: loop
    __shared__ float bs[NCLS];
    for (int idx = threadIdx.x; idx < H2 * NCLS; idx += 256) Ws[idx] = Wc[idx];
    if (threadIdx.x < NCLS) bs[threadIdx.x] = bc[threadIdx.x];
    __syncthreads();
    int i = blockIdx.x * blockDim.x + threadIdx.x;
    if (i >= N_NODES) return;
    float x[H2];
    #pragma unroll
    for (int k = 0; k < H2; ++k) x[k] = X2[(size_t)i * H2 + k];
    float lg[NCLS];
    #pragma unroll
    for (int c = 0; c < NCLS; ++c) {
        float acc = bs[c];
        #pragma unroll
        for (int k = 0; k < H2; ++k) acc += x[k] * Ws[k * NCLS + c];
        lg[c] = acc;
    }
    float m = lg[0];
    #pragma unroll
    for (int c = 1; c < NCLS; ++c) m = fmaxf(m, lg[c]);
    float s = 0.0f;
    #pragma unroll
    for (int c = 0; c < NCLS; ++c) s += expf(lg[c] - m);
    float lse = m + logf(s);
    #pragma unroll
    for (int c = 0; c < NCLS; ++c) out[(size_t)i * NCLS + c] = lg[c] - lse;
}

// ----------------------------------------------------------------
extern "C" void kernel_launch(void* const* d_in, const int* in_sizes, int n_in,
                              void* d_out, int out_size, void* d_ws, size_t ws_size,
                              hipStream_t stream) {
    const float* feature = (const float*)d_in[0];
    const int*   eidx    = (const int*)d_in[1];
    const float* W1      = (const float*)d_in[2];
    const float* b1      = (const float*)d_in[3];
    const float* W2      = (const float*)d_in[4];
    const float* b2      = (const float*)d_in[5];
    const float* Wc      = (const float*)d_in[6];
    const float* bc      = (const float*)d_in[7];
    float* out = (float*)d_out;

    const int E = in_sizes[1] / 2;
    const int* src = eidx;
    const int* dst = eidx + E;

    // workspace layout (4B units):
    //   dinv      [N] f32
    //   row_start [N], row_end [N] int
    //   scur      [NB*NSUB*16] uint ; ov_cnt [16] ; ov [OCAP]
    //   tmp_csr   [NB*NSUB*SCAP] uint (staged edges -> dense CSR in place)
    //   h1b       [N*64] bf16 (12.8 MB; layer 2 overlays h2b [N*32] bf16)
    //   x1        [N*64] f32  (25.6 MB; layer 2 overlays x2 [N*32] f32)
    float*          ws        = (float*)d_ws;
    float*          dinv      = ws;
    int*            row_start = (int*)(dinv + N_NODES);
    int*            row_end   = row_start + N_NODES;
    unsigned int*   scur      = (unsigned int*)(row_end + N_NODES);
    unsigned int*   ov_cnt    = scur + (size_t)NB * NSUB * 16;
    unsigned int*   ov        = ov_cnt + 16;
    unsigned int*   tmp_csr   = ov + OCAP;
    unsigned short* h1b       = (unsigned short*)(tmp_csr + (size_t)NB * NSUB * SCAP);
    float*          x1        = (float*)(h1b + (size_t)N_NODES * H1);
    unsigned short* h2b       = h1b;                 // overlay: h1 dead after pull1
    float*          x2        = x1;                  // overlay: x1 dead after gemm2

    // CSR build
    hipMemsetAsync(scur, 0, ((size_t)NB * NSUB * 16 + 16) * sizeof(unsigned int), stream);
    bin_kernel<<<(E + 255) / 256, 256, 0, stream>>>(src, dst, E, scur, tmp_csr, ov_cnt, ov);
    build_kernel<<<NB, 256, 0, stream>>>(scur, tmp_csr, ov_cnt, ov, src, dst,
                                         dinv, row_start, row_end);

    // layer 1
    gemm1_kernel<<<(N_NODES + 63) / 64, 256, 0, stream>>>(feature, W1, dinv, h1b);
    {
        unsigned int grid = (unsigned int)(((size_t)N_NODES * 64 + 255) / 256);
        pull1_kernel<<<grid, 256, 0, stream>>>(h1b, tmp_csr, row_start, row_end, dinv, b1, x1);
    }

    // layer 2
    gemm2_kernel<<<(N_NODES + 63) / 64, 256, 0, stream>>>(x1, W2, dinv, h2b);
    {
        unsigned int grid = (unsigned int)(((size_t)N_NODES * 64 + 255) / 256);
        pull2_kernel<<<grid, 256, 0, stream>>>(h2b, tmp_csr, row_start, row_end, dinv, b2, x2);
    }

    // classifier + log_softmax
    final_kernel<<<(N_NODES + 255) / 256, 256, 0, stream>>>(x2, Wc, bc, out);
}

// Round 7
// 534.213 us; speedup vs baseline: 2.6640x; 1.0086x over previous
//
#include <hip/hip_runtime.h>

#define N_NODES 100000
#define F_IN 128
#define H1 64
#define H2 32
#define NCLS 10

#define BS_N 256                                   // nodes per bucket
#define NB ((N_NODES + BS_N - 1) / BS_N)           // 391 buckets
#define NSUB 8                                     // per-XCD sub-regions
#define SCAP 2064                                  // slots per (bucket,xcd): mean 1023, +32 sigma.
                                                   // 2064 = 129*16 -> sub-region stride 129 cache
                                                   // lines (odd): breaks L2 set aliasing that caused
                                                   // 9x write amp at SCAP=4096 (2^14 B stride)
#define STCAP 9216                                 // LDS stage capacity: mean 8184, +11 sigma
#define OCAP (2 * 1024 * 1024)                     // overflow edge-id capacity (worst-case proof)

// HW_REG_XCC_ID = 20, bits [3:0]  -> getreg imm = ((4-1)<<11) | (0<<6) | 20
#define XCC_GETREG_IMM 6164

__device__ __forceinline__ unsigned short f2bf(float f) {   // RNE f32->bf16
    unsigned int u = __float_as_uint(f);
    return (unsigned short)((u + 0x7fffu + ((u >> 16) & 1u)) >> 16);
}
__device__ __forceinline__ float bf2f(unsigned short u) {
    return __uint_as_float((unsigned int)u << 16);
}

// ---------------------------------------------------------------- pass 1: bin edges by (dst bucket, XCD)
__global__ __launch_bounds__(256) void bin_kernel(const int* __restrict__ src,
                                                  const int* __restrict__ dst, int E,
                                                  unsigned int* __restrict__ scur,
                                                  unsigned int* __restrict__ tmp,
                                                  unsigned int* __restrict__ ov_cnt,
                                                  unsigned int* __restrict__ ov) {
    int e = blockIdx.x * 256 + threadIdx.x;
    if (e >= E) return;
    int xcc = __builtin_amdgcn_s_getreg(XCC_GETREG_IMM) & (NSUB - 1);  // wave-uniform
    int d = dst[e];
    int b = d >> 8;
    unsigned int pos = atomicAdd(&scur[(b * NSUB + xcc) * 16], 1u);
    if (pos < SCAP) {
        tmp[((size_t)b * NSUB + xcc) * SCAP + pos] =
            ((unsigned int)src[e] << 8) | (unsigned int)(d & 255);
    } else {
        unsigned int op = atomicAdd(ov_cnt, 1u);   // essentially never taken
        if (op < OCAP) ov[op] = (unsigned int)e;
    }
}

// ---------------------------------------------------------------- pass 2: per-bucket local CSR build
__global__ __launch_bounds__(256) void build_kernel(const unsigned int* __restrict__ scur,
                                                    unsigned int* __restrict__ tmp,
                                                    const unsigned int* __restrict__ ov_cnt,
                                                    const unsigned int* __restrict__ ov,
                                                    const int* __restrict__ src,
                                                    const int* __restrict__ dst,
                                                    float* __restrict__ dinv,
                                                    int* __restrict__ row_start,
                                                    int* __restrict__ row_end) {
    __shared__ unsigned int stage[STCAP];   // 36 KB
    __shared__ int degl[BS_N];
    __shared__ int rs_l[BS_N];
    __shared__ int curl[BS_N];
    __shared__ int wtot[4];
    __shared__ int stot;
    int b = blockIdx.x;
    int tid = threadIdx.x;

    int base = 0;
    #pragma unroll
    for (int x = 0; x < NSUB; ++x) {
        int c = (int)scur[(b * NSUB + x) * 16];
        if (c > SCAP) c = SCAP;
        for (int i = tid; i < c; i += 256) {
            int p = base + i;
            if (p < STCAP) stage[p] = tmp[((size_t)b * NSUB + x) * SCAP + i];
        }
        base += c;
    }
    if (base > STCAP) base = STCAP;
    if (tid == 0) stot = base;
    degl[tid] = 0;
    __syncthreads();

    unsigned int oc = *ov_cnt;          // overflow slow path (normally 0)
    if (oc) {
        if (oc > OCAP) oc = OCAP;
        for (unsigned int i = tid; i < oc; i += 256) {
            int e = (int)ov[i];
            int d = dst[e];
            if ((d >> 8) == b) {
                int p = atomicAdd(&stot, 1);
                if (p < STCAP)
                    stage[p] = ((unsigned int)src[e] << 8) | (unsigned int)(d & 255);
            }
        }
        __syncthreads();
    }
    int c = stot;
    if (c > STCAP) c = STCAP;

    for (int i = tid; i < c; i += 256) atomicAdd(&degl[stage[i] & 255], 1);
    __syncthreads();

    int lane = tid & 63, w = tid >> 6;
    int d = degl[tid];
    int x = d;
    #pragma unroll
    for (int off = 1; off < 64; off <<= 1) {
        int y = __shfl_up(x, off);
        if (lane >= off) x += y;
    }
    if (lane == 63) wtot[w] = x;
    __syncthreads();
    int pbase = 0;
    #pragma unroll
    for (int k = 0; k < 4; ++k) if (k < w) pbase += wtot[k];
    rs_l[tid] = pbase + x - d;
    curl[tid] = 0;
    __syncthreads();

    size_t gbase = (size_t)b * NSUB * SCAP;
    for (int i = tid; i < c; i += 256) {
        unsigned int en = stage[i];
        int dl = en & 255;
        int p = atomicAdd(&curl[dl], 1);
        tmp[gbase + rs_l[dl] + p] = en >> 8;
    }
    int node = b * BS_N + tid;
    if (node < N_NODES) {
        int deg = degl[tid];
        dinv[node] = rsqrtf((float)deg + 1.0f);
        row_start[node] = (int)gbase + rs_l[tid];
        row_end[node] = (int)gbase + rs_l[tid] + deg;
    }
}

// ---------------------------------------------------------------- GEMM 1: [N,128]@[128,64] -> bf16, scaled by dinv
// 64x64 tile, 256 threads, 4x4 accums; K staged in 2 halves; LDS ~49.4 KB
__global__ __launch_bounds__(256) void gemm1_kernel(const float* __restrict__ X,
                                                    const float* __restrict__ W,
                                                    const float* __restrict__ dinv,
                                                    unsigned short* __restrict__ H) {
    __shared__ float Xs[64][68];      // 17.4 KB, pad 68: 2-way-free bank pattern
    __shared__ float Ws[F_IN * H1];   // 32 KB
    int r0 = blockIdx.x * 64;
    const float4* W4 = (const float4*)W;
    float4* Ws4 = (float4*)Ws;
    for (int i = threadIdx.x; i < F_IN * H1 / 4; i += 256) Ws4[i] = W4[i];

    int tx = threadIdx.x & 15;        // col group: cols tx*4..+3
    int ty = threadIdx.x >> 4;        // row group: rows ty*4..+3
    float acc[4][4] = {};

    for (int kh = 0; kh < 2; ++kh) {
        __syncthreads();
        for (int it = 0; it < 4; ++it) {
            int idx = threadIdx.x + it * 256;
            int r = idx >> 4, k4 = idx & 15;
            int row = r0 + r;
            float4 v = (row < N_NODES)
                ? ((const float4*)X)[(size_t)row * 32 + kh * 16 + k4]
                : make_float4(0.f, 0.f, 0.f, 0.f);
            *(float4*)&Xs[r][k4 * 4] = v;
        }
        __syncthreads();
        #pragma unroll 8
        for (int k = 0; k < 64; ++k) {
            float4 wb = *(const float4*)&Ws[(kh * 64 + k) * H1 + tx * 4];
            float xa0 = Xs[ty * 4 + 0][k];
            float xa1 = Xs[ty * 4 + 1][k];
            float xa2 = Xs[ty * 4 + 2][k];
            float xa3 = Xs[ty * 4 + 3][k];
            acc[0][0] += xa0 * wb.x; acc[0][1] += xa0 * wb.y; acc[0][2] += xa0 * wb.z; acc[0][3] += xa0 * wb.w;
            acc[1][0] += xa1 * wb.x; acc[1][1] += xa1 * wb.y; acc[1][2] += xa1 * wb.z; acc[1][3] += xa1 * wb.w;
            acc[2][0] += xa2 * wb.x; acc[2][1] += xa2 * wb.y; acc[2][2] += xa2 * wb.z; acc[2][3] += xa2 * wb.w;
            acc[3][0] += xa3 * wb.x; acc[3][1] += xa3 * wb.y; acc[3][2] += xa3 * wb.z; acc[3][3] += xa3 * wb.w;
        }
    }
    #pragma unroll
    for (int i = 0; i < 4; ++i) {
        int row = r0 + ty * 4 + i;
        if (row < N_NODES) {
            float dv = dinv[row];
            unsigned int lo = (unsigned int)f2bf(acc[i][0] * dv) |
                              ((unsigned int)f2bf(acc[i][1] * dv) << 16);
            unsigned int hi = (unsigned int)f2bf(acc[i][2] * dv) |
                              ((unsigned int)f2bf(acc[i][3] * dv) << 16);
            *(uint2*)&H[(size_t)row * H1 + tx * 4] = make_uint2(lo, hi);
        }
    }
}

// ---------------------------------------------------------------- GEMM 2: [N,64]@[64,32] -> bf16, scaled by dinv
__global__ __launch_bounds__(256) void gemm2_kernel(const float* __restrict__ X,
                                                    const float* __restrict__ W,
                                                    const float* __restrict__ dinv,
                                                    unsigned short* __restrict__ H) {
    __shared__ float Xs[64][68];     // 17.4 KB
    __shared__ float Ws[H1 * H2];    // 8 KB
    int r0 = blockIdx.x * 64;
    const float4* W4 = (const float4*)W;
    float4* Ws4 = (float4*)Ws;
    for (int i = threadIdx.x; i < H1 * H2 / 4; i += 256) Ws4[i] = W4[i];
    for (int it = 0; it < 4; ++it) {
        int idx = threadIdx.x + it * 256;
        int r = idx >> 4, k4 = idx & 15;
        int row = r0 + r;
        float4 v = (row < N_NODES)
            ? ((const float4*)X)[(size_t)row * 16 + k4]
            : make_float4(0.f, 0.f, 0.f, 0.f);
        *(float4*)&Xs[r][k4 * 4] = v;
    }
    __syncthreads();
    int tx = threadIdx.x & 15;       // col pair: cols tx*2..+1
    int ty = threadIdx.x >> 4;       // rows ty*4..+3
    float acc[4][2] = {};
    #pragma unroll 8
    for (int k = 0; k < 64; ++k) {
        float2 wb = *(const float2*)&Ws[k * H2 + tx * 2];
        float xa0 = Xs[ty * 4 + 0][k];
        float xa1 = Xs[ty * 4 + 1][k];
        float xa2 = Xs[ty * 4 + 2][k];
        float xa3 = Xs[ty * 4 + 3][k];
        acc[0][0] += xa0 * wb.x; acc[0][1] += xa0 * wb.y;
        acc[1][0] += xa1 * wb.x; acc[1][1] += xa1 * wb.y;
        acc[2][0] += xa2 * wb.x; acc[2][1] += xa2 * wb.y;
        acc[3][0] += xa3 * wb.x; acc[3][1] += xa3 * wb.y;
    }
    #pragma unroll
    for (int i = 0; i < 4; ++i) {
        int row = r0 + ty * 4 + i;
        if (row < N_NODES) {
            float dv = dinv[row];
            unsigned int v = (unsigned int)f2bf(acc[i][0] * dv) |
                             ((unsigned int)f2bf(acc[i][1] * dv) << 16);
            *(unsigned int*)&H[(size_t)row * H2 + tx * 2] = v;
        }
    }
}

// ---------------------------------------------------------------- pull aggregation, F=64 (bf16 gathers)
__global__ __launch_bounds__(256) void pull1_kernel(const unsigned short* __restrict__ h,
                                                    const unsigned int* __restrict__ csr,
                                                    const int* __restrict__ row_start,
                                                    const int* __restrict__ row_end,
                                                    const float* __restrict__ dinv,
                                                    const float* __restrict__ b,
                                                    float* __restrict__ xout) {
    int wave = (blockIdx.x * 256 + threadIdx.x) >> 6;
    int f = threadIdx.x & 63;
    if (wave >= N_NODES) return;
    int i = wave;
    int e0 = row_start[i], e1 = row_end[i];
    float acc = bf2f(h[(size_t)i * H1 + f]);   // self loop
    int e = e0;
    for (; e + 3 < e1; e += 4) {               // 4-way ILP
        int s0 = csr[e], s1 = csr[e + 1], s2 = csr[e + 2], s3 = csr[e + 3];
        acc += bf2f(h[(size_t)s0 * H1 + f]);
        acc += bf2f(h[(size_t)s1 * H1 + f]);
        acc += bf2f(h[(size_t)s2 * H1 + f]);
        acc += bf2f(h[(size_t)s3 * H1 + f]);
    }
    for (; e < e1; ++e) acc += bf2f(h[(size_t)csr[e] * H1 + f]);
    float v = dinv[i] * acc + b[f];
    xout[(size_t)i * H1 + f] = fmaxf(v, 0.0f);
}

// ---------------------------------------------------------------- pull aggregation, F=32 (bf16 gathers)
__global__ __launch_bounds__(256) void pull2_kernel(const unsigned short* __restrict__ h,
                                                    const unsigned int* __restrict__ csr,
                                                    const int* __restrict__ row_start,
                                                    const int* __restrict__ row_end,
                                                    const float* __restrict__ dinv,
                                                    const float* __restrict__ b,
                                                    float* __restrict__ xout) {
    int wave = (blockIdx.x * 256 + threadIdx.x) >> 6;
    int lane = threadIdx.x & 63;
    int half = lane >> 5;
    int f = lane & 31;
    if (wave >= N_NODES) return;
    int i = wave;
    int e0 = row_start[i], e1 = row_end[i];
    float acc = 0.0f;
    int e = e0 + half;
    for (; e + 2 < e1; e += 4) {
        int s0 = csr[e], s1 = csr[e + 2];
        acc += bf2f(h[(size_t)s0 * H2 + f]);
        acc += bf2f(h[(size_t)s1 * H2 + f]);
    }
    for (; e < e1; e += 2) acc += bf2f(h[(size_t)csr[e] * H2 + f]);
    acc += __shfl_xor(acc, 32);
    if (half == 0) {
        float v = dinv[i] * (acc + bf2f(h[(size_t)i * H2 + f])) + b[f];
        xout[(size_t)i * H2 + f] = fmaxf(v, 0.0f);
    }
}

// ---------------------------------------------------------------- classifier + log_softmax
__global__ __launch_bounds__(256) void final_kernel(const float* __restrict__ X2,
                                                    const float* __restrict__ Wc,
                                                    const float* __restrict__ bc,
                                                    float* __restrict__ out) {
    __shared__ float Ws[H2 * NCLS];   // 320 floats > 256 threads: loop
    __shared__ float bs[NCLS];
    for (int idx = threadIdx.x; idx < H2 * NCLS; idx += 256) Ws[idx] = Wc[idx];
    if (threadIdx.x < NCLS) bs[threadIdx.x] = bc[threadIdx.x];
    __syncthreads();
    int i = blockIdx.x * blockDim.x + threadIdx.x;
    if (i >= N_NODES) return;
    float x[H2];
    #pragma unroll
    for (int k = 0; k < H2; ++k) x[k] = X2[(size_t)i * H2 + k];
    float lg[NCLS];
    #pragma unroll
    for (int c = 0; c < NCLS; ++c) {
        float acc = bs[c];
        #pragma unroll
        for (int k = 0; k < H2; ++k) acc += x[k] * Ws[k * NCLS + c];
        lg[c] = acc;
    }
    float m = lg[0];
    #pragma unroll
    for (int c = 1; c < NCLS; ++c) m = fmaxf(m, lg[c]);
    float s = 0.0f;
    #pragma unroll
    for (int c = 0; c < NCLS; ++c) s += expf(lg[c] - m);
    float lse = m + logf(s);
    #pragma unroll
    for (int c = 0; c < NCLS; ++c) out[(size_t)i * NCLS + c] = lg[c] - lse;
}

// ----------------------------------------------------------------
extern "C" void kernel_launch(void* const* d_in, const int* in_sizes, int n_in,
                              void* d_out, int out_size, void* d_ws, size_t ws_size,
                              hipStream_t stream) {
    const float* feature = (const float*)d_in[0];
    const int*   eidx    = (const int*)d_in[1];
    const float* W1      = (const float*)d_in[2];
    const float* b1      = (const float*)d_in[3];
    const float* W2      = (const float*)d_in[4];
    const float* b2      = (const float*)d_in[5];
    const float* Wc      = (const float*)d_in[6];
    const float* bc      = (const float*)d_in[7];
    float* out = (float*)d_out;

    const int E = in_sizes[1] / 2;
    const int* src = eidx;
    const int* dst = eidx + E;

    // workspace layout (4B units):
    //   dinv [N] f32 ; row_start [N], row_end [N] int
    //   scur [NB*NSUB*16] uint ; ov_cnt [16] ; ov [OCAP]
    //   tmp_csr [NB*NSUB*SCAP] uint (~25.8 MB; staged edges -> dense CSR in place)
    //   h1b [N*64] bf16 (12.8 MB; layer 2 overlays h2b [N*32] bf16)
    //   x1  [N*64] f32  (25.6 MB; layer 2 overlays x2 [N*32] f32)
    float*          ws        = (float*)d_ws;
    float*          dinv      = ws;
    int*            row_start = (int*)(dinv + N_NODES);
    int*            row_end   = row_start + N_NODES;
    unsigned int*   scur      = (unsigned int*)(row_end + N_NODES);
    unsigned int*   ov_cnt    = scur + (size_t)NB * NSUB * 16;
    unsigned int*   ov        = ov_cnt + 16;
    unsigned int*   tmp_csr   = ov + OCAP;
    unsigned short* h1b       = (unsigned short*)(tmp_csr + (size_t)NB * NSUB * SCAP);
    float*          x1        = (float*)(h1b + (size_t)N_NODES * H1);
    unsigned short* h2b       = h1b;                 // overlay: h1 dead after pull1
    float*          x2        = x1;                  // overlay: x1 dead after gemm2

    // CSR build
    hipMemsetAsync(scur, 0, ((size_t)NB * NSUB * 16 + 16) * sizeof(unsigned int), stream);
    bin_kernel<<<(E + 255) / 256, 256, 0, stream>>>(src, dst, E, scur, tmp_csr, ov_cnt, ov);
    build_kernel<<<NB, 256, 0, stream>>>(scur, tmp_csr, ov_cnt, ov, src, dst,
                                         dinv, row_start, row_end);

    // layer 1
    gemm1_kernel<<<(N_NODES + 63) / 64, 256, 0, stream>>>(feature, W1, dinv, h1b);
    {
        unsigned int grid = (unsigned int)(((size_t)N_NODES * 64 + 255) / 256);
        pull1_kernel<<<grid, 256, 0, stream>>>(h1b, tmp_csr, row_start, row_end, dinv, b1, x1);
    }

    // layer 2
    gemm2_kernel<<<(N_NODES + 63) / 64, 256, 0, stream>>>(x1, W2, dinv, h2b);
    {
        unsigned int grid = (unsigned int)(((size_t)N_NODES * 64 + 255) / 256);
        pull2_kernel<<<grid, 256, 0, stream>>>(h2b, tmp_csr, row_start, row_end, dinv, b2, x2);
    }

    // classifier + log_softmax
    final_kernel<<<(N_NODES + 255) / 256, 256, 0, stream>>>(x2, Wc, bc, out);
}

// Round 8
// 404.440 us; speedup vs baseline: 3.5188x; 1.3209x over previous
//
#include <hip/hip_runtime.h>

#define N_NODES 100000
#define F_IN 128
#define H1 64
#define H2 32
#define NCLS 10

#define BS_N 256                                   // nodes per bucket
#define NBUCK ((N_NODES + BS_N - 1) / BS_N)        // 391 buckets
#define LCAP 32                                    // LDS slots per bucket
#define MCAP 9216                                  // main entries per bucket (16-aligned fills only)
#define OVCAP 6144                                 // overflow entries per bucket (mean ~1920, +huge margin)
#define STCAP 9216                                 // build LDS stage: mean 8192, +11 sigma
#define BIN_WG 256                                 // bin workgroups (1/CU), 512 thr each

__device__ __forceinline__ unsigned short f2bf(float f) {   // RNE f32->bf16
    unsigned int u = __float_as_uint(f);
    return (unsigned short)((u + 0x7fffu + ((u >> 16) & 1u)) >> 16);
}
__device__ __forceinline__ float bf2f(unsigned short u) {
    return __uint_as_float((unsigned int)u << 16);
}

// ---------------------------------------------------------------- pass 1: LDS-staged binning
// Scattered-line-op ceiling (~20-40 ops/ns, R2/R3/R4/R7 evidence) means per-edge global
// atomics are the floor. Stage in LDS, flush 16-entry full lines: 1 atomic + 1 line per
// 16 edges instead of 2 line-ops per edge.
__global__ __launch_bounds__(512) void bin_kernel(const int* __restrict__ src,
                                                  const int* __restrict__ dst, int E,
                                                  unsigned int* __restrict__ gcur,   // [NBUCK*16]
                                                  unsigned int* __restrict__ mainr,  // [NBUCK*MCAP]
                                                  unsigned int* __restrict__ ovcnt,  // [NBUCK*16]
                                                  unsigned int* __restrict__ ovbuf) {// [NBUCK*OVCAP]
    __shared__ unsigned int buf[NBUCK][LCAP];   // 50.0 KB
    __shared__ int cnt[NBUCK];
    int tid = threadIdx.x;
    for (int b = tid; b < NBUCK; b += 512) cnt[b] = 0;

    int chunk = (E + gridDim.x - 1) / gridDim.x;
    int e_lo = blockIdx.x * chunk;
    int e_hi = min(e_lo + chunk, E);

    int d0 = 0, s0 = 0, d1 = 0, s1 = 0;
    {   // prefetch first batch
        int ea = e_lo + tid, eb = e_lo + 512 + tid;
        if (ea < e_hi) { d0 = dst[ea]; s0 = src[ea]; }
        if (eb < e_hi) { d1 = dst[eb]; s1 = src[eb]; }
    }
    __syncthreads();

    for (int base = e_lo; base < e_hi; base += 1024) {
        // append current batch (2 edges/thread) into LDS buckets
        if (base + tid < e_hi) {
            int b = d0 >> 8;
            unsigned int en = ((unsigned int)s0 << 8) | (unsigned int)(d0 & 255);
            int p = atomicAdd(&cnt[b], 1);
            if (p < LCAP) buf[b][p] = en;
            else {  // hard overflow: ~never (needs >17 hits of one bucket in one batch)
                unsigned int op = atomicAdd(&ovcnt[b * 16], 1u);
                if (op < OVCAP) ovbuf[(size_t)b * OVCAP + op] = en;
            }
        }
        if (base + 512 + tid < e_hi) {
            int b = d1 >> 8;
            unsigned int en = ((unsigned int)s1 << 8) | (unsigned int)(d1 & 255);
            int p = atomicAdd(&cnt[b], 1);
            if (p < LCAP) buf[b][p] = en;
            else {
                unsigned int op = atomicAdd(&ovcnt[b * 16], 1u);
                if (op < OVCAP) ovbuf[(size_t)b * OVCAP + op] = en;
            }
        }
        __syncthreads();
        // prefetch next batch (VMEM in flight across the flush phase)
        {
            int nb = base + 1024;
            int ea = nb + tid, eb = nb + 512 + tid;
            if (ea < e_hi) { d0 = dst[ea]; s0 = src[ea]; }
            if (eb < e_hi) { d1 = dst[eb]; s1 = src[eb]; }
        }
        // flush: aligned 16-entry chunks -> full 64B lines, one atomic per chunk
        for (int b = tid; b < NBUCK; b += 512) {
            int c = cnt[b]; if (c > LCAP) c = LCAP;
            int nf = c & ~15;
            if (nf) {
                unsigned int gb = atomicAdd(&gcur[b * 16], (unsigned int)nf);
                if (gb + (unsigned)nf <= MCAP) {
                    for (int k = 0; k < nf; k += 4) {
                        uint4 v = make_uint4(buf[b][k], buf[b][k + 1],
                                             buf[b][k + 2], buf[b][k + 3]);
                        *(uint4*)&mainr[(size_t)b * MCAP + gb + k] = v;
                    }
                } else {  // ~never: bucket heavier than +11 sigma
                    unsigned int op = atomicAdd(&ovcnt[b * 16], (unsigned int)nf);
                    for (int k = 0; k < nf; ++k)
                        if (op + k < OVCAP) ovbuf[(size_t)b * OVCAP + op + k] = buf[b][k];
                }
                int rem = c - nf;
                for (int k = 0; k < rem; ++k) buf[b][k] = buf[b][nf + k];
                cnt[b] = rem;
            } else {
                cnt[b] = c;
            }
        }
        __syncthreads();
    }
    // final flush: remainders (<=15 per bucket) -> overflow region
    for (int b = tid; b < NBUCK; b += 512) {
        int c = cnt[b]; if (c > LCAP) c = LCAP;
        if (c) {
            unsigned int ob = atomicAdd(&ovcnt[b * 16], (unsigned int)c);
            for (int k = 0; k < c; ++k)
                if (ob + k < OVCAP) ovbuf[(size_t)b * OVCAP + ob + k] = buf[b][k];
        }
    }
}

// ---------------------------------------------------------------- pass 2: per-bucket local CSR build
__global__ __launch_bounds__(256) void build_kernel(const unsigned int* __restrict__ gcur,
                                                    unsigned int* __restrict__ mainr,
                                                    const unsigned int* __restrict__ ovcnt,
                                                    const unsigned int* __restrict__ ovbuf,
                                                    float* __restrict__ dinv,
                                                    int* __restrict__ row_start,
                                                    int* __restrict__ row_end) {
    __shared__ unsigned int stage[STCAP];   // 36 KB
    __shared__ int degl[BS_N];
    __shared__ int rs_l[BS_N];
    __shared__ int curl[BS_N];
    __shared__ int wtot[4];
    int b = blockIdx.x;
    int tid = threadIdx.x;

    int cm = (int)gcur[b * 16]; if (cm > MCAP) cm = MCAP;
    for (int i = tid; i < cm; i += 256) stage[i] = mainr[(size_t)b * MCAP + i];
    int co = (int)ovcnt[b * 16]; if (co > OVCAP) co = OVCAP;
    for (int i = tid; i < co; i += 256) {
        int p = cm + i;
        if (p < STCAP) stage[p] = ovbuf[(size_t)b * OVCAP + i];
    }
    int c = cm + co; if (c > STCAP) c = STCAP;
    degl[tid] = 0;
    __syncthreads();

    for (int i = tid; i < c; i += 256) atomicAdd(&degl[stage[i] & 255], 1);
    __syncthreads();

    int lane = tid & 63, w = tid >> 6;
    int d = degl[tid];
    int x = d;
    #pragma unroll
    for (int off = 1; off < 64; off <<= 1) {
        int y = __shfl_up(x, off);
        if (lane >= off) x += y;
    }
    if (lane == 63) wtot[w] = x;
    __syncthreads();
    int pbase = 0;
    #pragma unroll
    for (int k = 0; k < 4; ++k) if (k < w) pbase += wtot[k];
    rs_l[tid] = pbase + x - d;
    curl[tid] = 0;
    __syncthreads();

    size_t gbase = (size_t)b * MCAP;
    for (int i = tid; i < c; i += 256) {
        unsigned int en = stage[i];
        int dl = en & 255;
        int p = atomicAdd(&curl[dl], 1);
        mainr[gbase + rs_l[dl] + p] = en >> 8;
    }
    int node = b * BS_N + tid;
    if (node < N_NODES) {
        int deg = degl[tid];
        dinv[node] = rsqrtf((float)deg + 1.0f);
        row_start[node] = (int)gbase + rs_l[tid];
        row_end[node] = (int)gbase + rs_l[tid] + deg;
    }
}

// ---------------------------------------------------------------- GEMM 1: [N,128]@[128,64] -> bf16, scaled by dinv
__global__ __launch_bounds__(256) void gemm1_kernel(const float* __restrict__ X,
                                                    const float* __restrict__ W,
                                                    const float* __restrict__ dinv,
                                                    unsigned short* __restrict__ H) {
    __shared__ float Xs[64][68];      // pad 68: 2-way-free bank pattern
    __shared__ float Ws[F_IN * H1];   // 32 KB
    int r0 = blockIdx.x * 64;
    const float4* W4 = (const float4*)W;
    float4* Ws4 = (float4*)Ws;
    for (int i = threadIdx.x; i < F_IN * H1 / 4; i += 256) Ws4[i] = W4[i];

    int tx = threadIdx.x & 15;
    int ty = threadIdx.x >> 4;
    float acc[4][4] = {};

    for (int kh = 0; kh < 2; ++kh) {
        __syncthreads();
        for (int it = 0; it < 4; ++it) {
            int idx = threadIdx.x + it * 256;
            int r = idx >> 4, k4 = idx & 15;
            int row = r0 + r;
            float4 v = (row < N_NODES)
                ? ((const float4*)X)[(size_t)row * 32 + kh * 16 + k4]
                : make_float4(0.f, 0.f, 0.f, 0.f);
            *(float4*)&Xs[r][k4 * 4] = v;
        }
        __syncthreads();
        #pragma unroll 8
        for (int k = 0; k < 64; ++k) {
            float4 wb = *(const float4*)&Ws[(kh * 64 + k) * H1 + tx * 4];
            float xa0 = Xs[ty * 4 + 0][k];
            float xa1 = Xs[ty * 4 + 1][k];
            float xa2 = Xs[ty * 4 + 2][k];
            float xa3 = Xs[ty * 4 + 3][k];
            acc[0][0] += xa0 * wb.x; acc[0][1] += xa0 * wb.y; acc[0][2] += xa0 * wb.z; acc[0][3] += xa0 * wb.w;
            acc[1][0] += xa1 * wb.x; acc[1][1] += xa1 * wb.y; acc[1][2] += xa1 * wb.z; acc[1][3] += xa1 * wb.w;
            acc[2][0] += xa2 * wb.x; acc[2][1] += xa2 * wb.y; acc[2][2] += xa2 * wb.z; acc[2][3] += xa2 * wb.w;
            acc[3][0] += xa3 * wb.x; acc[3][1] += xa3 * wb.y; acc[3][2] += xa3 * wb.z; acc[3][3] += xa3 * wb.w;
        }
    }
    #pragma unroll
    for (int i = 0; i < 4; ++i) {
        int row = r0 + ty * 4 + i;
        if (row < N_NODES) {
            float dv = dinv[row];
            unsigned int lo = (unsigned int)f2bf(acc[i][0] * dv) |
                              ((unsigned int)f2bf(acc[i][1] * dv) << 16);
            unsigned int hi = (unsigned int)f2bf(acc[i][2] * dv) |
                              ((unsigned int)f2bf(acc[i][3] * dv) << 16);
            *(uint2*)&H[(size_t)row * H1 + tx * 4] = make_uint2(lo, hi);
        }
    }
}

// ---------------------------------------------------------------- GEMM 2: [N,64]@[64,32] -> bf16, scaled by dinv
__global__ __launch_bounds__(256) void gemm2_kernel(const float* __restrict__ X,
                                                    const float* __restrict__ W,
                                                    const float* __restrict__ dinv,
                                                    unsigned short* __restrict__ H) {
    __shared__ float Xs[64][68];
    __shared__ float Ws[H1 * H2];
    int r0 = blockIdx.x * 64;
    const float4* W4 = (const float4*)W;
    float4* Ws4 = (float4*)Ws;
    for (int i = threadIdx.x; i < H1 * H2 / 4; i += 256) Ws4[i] = W4[i];
    for (int it = 0; it < 4; ++it) {
        int idx = threadIdx.x + it * 256;
        int r = idx >> 4, k4 = idx & 15;
        int row = r0 + r;
        float4 v = (row < N_NODES)
            ? ((const float4*)X)[(size_t)row * 16 + k4]
            : make_float4(0.f, 0.f, 0.f, 0.f);
        *(float4*)&Xs[r][k4 * 4] = v;
    }
    __syncthreads();
    int tx = threadIdx.x & 15;
    int ty = threadIdx.x >> 4;
    float acc[4][2] = {};
    #pragma unroll 8
    for (int k = 0; k < 64; ++k) {
        float2 wb = *(const float2*)&Ws[k * H2 + tx * 2];
        float xa0 = Xs[ty * 4 + 0][k];
        float xa1 = Xs[ty * 4 + 1][k];
        float xa2 = Xs[ty * 4 + 2][k];
        float xa3 = Xs[ty * 4 + 3][k];
        acc[0][0] += xa0 * wb.x; acc[0][1] += xa0 * wb.y;
        acc[1][0] += xa1 * wb.x; acc[1][1] += xa1 * wb.y;
        acc[2][0] += xa2 * wb.x; acc[2][1] += xa2 * wb.y;
        acc[3][0] += xa3 * wb.x; acc[3][1] += xa3 * wb.y;
    }
    #pragma unroll
    for (int i = 0; i < 4; ++i) {
        int row = r0 + ty * 4 + i;
        if (row < N_NODES) {
            float dv = dinv[row];
            unsigned int v = (unsigned int)f2bf(acc[i][0] * dv) |
                             ((unsigned int)f2bf(acc[i][1] * dv) << 16);
            *(unsigned int*)&H[(size_t)row * H2 + tx * 2] = v;
        }
    }
}

// ---------------------------------------------------------------- pull aggregation, F=64 (bf16 gathers)
__global__ __launch_bounds__(256) void pull1_kernel(const unsigned short* __restrict__ h,
                                                    const unsigned int* __restrict__ csr,
                                                    const int* __restrict__ row_start,
                                                    const int* __restrict__ row_end,
                                                    const float* __restrict__ dinv,
                                                    const float* __restrict__ b,
                                                    float* __restrict__ xout) {
    int wave = (blockIdx.x * 256 + threadIdx.x) >> 6;
    int f = threadIdx.x & 63;
    if (wave >= N_NODES) return;
    int i = wave;
    int e0 = row_start[i], e1 = row_end[i];
    float acc = bf2f(h[(size_t)i * H1 + f]);   // self loop
    int e = e0;
    for (; e + 3 < e1; e += 4) {               // 4-way ILP
        int s0 = csr[e], s1 = csr[e + 1], s2 = csr[e + 2], s3 = csr[e + 3];
        acc += bf2f(h[(size_t)s0 * H1 + f]);
        acc += bf2f(h[(size_t)s1 * H1 + f]);
        acc += bf2f(h[(size_t)s2 * H1 + f]);
        acc += bf2f(h[(size_t)s3 * H1 + f]);
    }
    for (; e < e1; ++e) acc += bf2f(h[(size_t)csr[e] * H1 + f]);
    float v = dinv[i] * acc + b[f];
    xout[(size_t)i * H1 + f] = fmaxf(v, 0.0f);
}

// ---------------------------------------------------------------- pull aggregation, F=32 (bf16 gathers)
__global__ __launch_bounds__(256) void pull2_kernel(const unsigned short* __restrict__ h,
                                                    const unsigned int* __restrict__ csr,
                                                    const int* __restrict__ row_start,
                                                    const int* __restrict__ row_end,
                                                    const float* __restrict__ dinv,
                                                    const float* __restrict__ b,
                                                    float* __restrict__ xout) {
    int wave = (blockIdx.x * 256 + threadIdx.x) >> 6;
    int lane = threadIdx.x & 63;
    int half = lane >> 5;
    int f = lane & 31;
    if (wave >= N_NODES) return;
    int i = wave;
    int e0 = row_start[i], e1 = row_end[i];
    float acc = 0.0f;
    int e = e0 + half;
    for (; e + 2 < e1; e += 4) {
        int s0 = csr[e], s1 = csr[e + 2];
        acc += bf2f(h[(size_t)s0 * H2 + f]);
        acc += bf2f(h[(size_t)s1 * H2 + f]);
    }
    for (; e < e1; e += 2) acc += bf2f(h[(size_t)csr[e] * H2 + f]);
    acc += __shfl_xor(acc, 32);
    if (half == 0) {
        float v = dinv[i] * (acc + bf2f(h[(size_t)i * H2 + f])) + b[f];
        xout[(size_t)i * H2 + f] = fmaxf(v, 0.0f);
    }
}

// ---------------------------------------------------------------- classifier + log_softmax
__global__ __launch_bounds__(256) void final_kernel(const float* __restrict__ X2,
                                                    const float* __restrict__ Wc,
                                                    const float* __restrict__ bc,
                                                    float* __restrict__ out) {
    __shared__ float Ws[H2 * NCLS];   // 320 floats > 256 threads: loop
    __shared__ float bs[NCLS];
    for (int idx = threadIdx.x; idx < H2 * NCLS; idx += 256) Ws[idx] = Wc[idx];
    if (threadIdx.x < NCLS) bs[threadIdx.x] = bc[threadIdx.x];
    __syncthreads();
    int i = blockIdx.x * blockDim.x + threadIdx.x;
    if (i >= N_NODES) return;
    float x[H2];
    #pragma unroll
    for (int k = 0; k < H2; ++k) x[k] = X2[(size_t)i * H2 + k];
    float lg[NCLS];
    #pragma unroll
    for (int c = 0; c < NCLS; ++c) {
        float acc = bs[c];
        #pragma unroll
        for (int k = 0; k < H2; ++k) acc += x[k] * Ws[k * NCLS + c];
        lg[c] = acc;
    }
    float m = lg[0];
    #pragma unroll
    for (int c = 1; c < NCLS; ++c) m = fmaxf(m, lg[c]);
    float s = 0.0f;
    #pragma unroll
    for (int c = 0; c < NCLS; ++c) s += expf(lg[c] - m);
    float lse = m + logf(s);
    #pragma unroll
    for (int c = 0; c < NCLS; ++c) out[(size_t)i * NCLS + c] = lg[c] - lse;
}

// ----------------------------------------------------------------
extern "C" void kernel_launch(void* const* d_in, const int* in_sizes, int n_in,
                              void* d_out, int out_size, void* d_ws, size_t ws_size,
                              hipStream_t stream) {
    const float* feature = (const float*)d_in[0];
    const int*   eidx    = (const int*)d_in[1];
    const float* W1      = (const float*)d_in[2];
    const float* b1      = (const float*)d_in[3];
    const float* W2      = (const float*)d_in[4];
    const float* b2      = (const float*)d_in[5];
    const float* Wc      = (const float*)d_in[6];
    const float* bc      = (const float*)d_in[7];
    float* out = (float*)d_out;

    const int E = in_sizes[1] / 2;
    const int* src = eidx;
    const int* dst = eidx + E;

    // workspace layout (4B units):
    //   dinv [N] f32 ; row_start [N], row_end [N] int
    //   gcur [NBUCK*16] + ovcnt [NBUCK*16] (contiguous, one memset)
    //   ovbuf [NBUCK*OVCAP] (9.6 MB) ; mainr [NBUCK*MCAP] (14.4 MB, becomes dense CSR)
    //   h1b [N*64] bf16 (12.8 MB; layer 2 overlays h2b [N*32])
    //   x1  [N*64] f32  (25.6 MB; layer 2 overlays x2 [N*32])
    float*          ws        = (float*)d_ws;
    float*          dinv      = ws;
    int*            row_start = (int*)(dinv + N_NODES);
    int*            row_end   = row_start + N_NODES;
    unsigned int*   gcur      = (unsigned int*)(row_end + N_NODES);
    unsigned int*   ovcnt     = gcur + (size_t)NBUCK * 16;
    unsigned int*   ovbuf     = ovcnt + (size_t)NBUCK * 16;
    unsigned int*   mainr     = ovbuf + (size_t)NBUCK * OVCAP;
    unsigned short* h1b       = (unsigned short*)(mainr + (size_t)NBUCK * MCAP);
    float*          x1        = (float*)(h1b + (size_t)N_NODES * H1);
    unsigned short* h2b       = h1b;                 // overlay: h1 dead after pull1
    float*          x2        = x1;                  // overlay: x1 dead after gemm2

    // CSR build
    hipMemsetAsync(gcur, 0, (size_t)NBUCK * 32 * sizeof(unsigned int), stream);
    bin_kernel<<<BIN_WG, 512, 0, stream>>>(src, dst, E, gcur, mainr, ovcnt, ovbuf);
    build_kernel<<<NBUCK, 256, 0, stream>>>(gcur, mainr, ovcnt, ovbuf,
                                            dinv, row_start, row_end);

    // layer 1
    gemm1_kernel<<<(N_NODES + 63) / 64, 256, 0, stream>>>(feature, W1, dinv, h1b);
    {
        unsigned int grid = (unsigned int)(((size_t)N_NODES * 64 + 255) / 256);
        pull1_kernel<<<grid, 256, 0, stream>>>(h1b, mainr, row_start, row_end, dinv, b1, x1);
    }

    // layer 2
    gemm2_kernel<<<(N_NODES + 63) / 64, 256, 0, stream>>>(x1, W2, dinv, h2b);
    {
        unsigned int grid = (unsigned int)(((size_t)N_NODES * 64 + 255) / 256);
        pull2_kernel<<<grid, 256, 0, stream>>>(h2b, mainr, row_start, row_end, dinv, b2, x2);
    }

    // classifier + log_softmax
    final_kernel<<<(N_NODES + 255) / 256, 256, 0, stream>>>(x2, Wc, bc, out);
}

// Round 9
// 311.398 us; speedup vs baseline: 4.5702x; 1.2988x over previous
//
#include <hip/hip_runtime.h>

#define N_NODES 100000
#define F_IN 128
#define H1 64
#define H2 32
#define NCLS 10

#define BS_N 256                                   // nodes per bucket
#define NBUCK ((N_NODES + BS_N - 1) / BS_N)        // 391 buckets
#define LCAP 32                                    // LDS slots per bucket
#define MCAP 9216                                  // main entries per bucket (16-aligned fills only)
#define OVCAP 6144                                 // overflow entries per bucket
#define STCAP 9216                                 // build LDS stage: mean 8192, +11 sigma
#define BIN_WG 256                                 // bin workgroups (1/CU), 512 thr each

__device__ __forceinline__ unsigned short f2bf(float f) {   // RNE f32->bf16
    unsigned int u = __float_as_uint(f);
    return (unsigned short)((u + 0x7fffu + ((u >> 16) & 1u)) >> 16);
}
__device__ __forceinline__ float bf2f(unsigned short u) {
    return __uint_as_float((unsigned int)u << 16);
}
// accumulate 2 packed bf16 (one dword) into a[0],a[1] — shift/and only, no cvt
__device__ __forceinline__ void accp(float* a, unsigned int u) {
    a[0] += __uint_as_float(u << 16);
    a[1] += __uint_as_float(u & 0xffff0000u);
}
__device__ __forceinline__ void accp4(float* a, uint4 v) {
    accp(a + 0, v.x); accp(a + 2, v.y); accp(a + 4, v.z); accp(a + 6, v.w);
}

// ---------------------------------------------------------------- pass 1: LDS-staged binning
// Scattered-line-op ceiling (~20-40 ops/ns) -> stage in LDS, flush 16-entry full lines.
__global__ __launch_bounds__(512) void bin_kernel(const int* __restrict__ src,
                                                  const int* __restrict__ dst, int E,
                                                  unsigned int* __restrict__ gcur,
                                                  unsigned int* __restrict__ mainr,
                                                  unsigned int* __restrict__ ovcnt,
                                                  unsigned int* __restrict__ ovbuf) {
    __shared__ unsigned int buf[NBUCK][LCAP];   // 50.0 KB
    __shared__ int cnt[NBUCK];
    int tid = threadIdx.x;
    for (int b = tid; b < NBUCK; b += 512) cnt[b] = 0;

    int chunk = (E + gridDim.x - 1) / gridDim.x;
    int e_lo = blockIdx.x * chunk;
    int e_hi = min(e_lo + chunk, E);

    int d0 = 0, s0 = 0, d1 = 0, s1 = 0;
    {
        int ea = e_lo + tid, eb = e_lo + 512 + tid;
        if (ea < e_hi) { d0 = dst[ea]; s0 = src[ea]; }
        if (eb < e_hi) { d1 = dst[eb]; s1 = src[eb]; }
    }
    __syncthreads();

    for (int base = e_lo; base < e_hi; base += 1024) {
        if (base + tid < e_hi) {
            int b = d0 >> 8;
            unsigned int en = ((unsigned int)s0 << 8) | (unsigned int)(d0 & 255);
            int p = atomicAdd(&cnt[b], 1);
            if (p < LCAP) buf[b][p] = en;
            else {
                unsigned int op = atomicAdd(&ovcnt[b * 16], 1u);
                if (op < OVCAP) ovbuf[(size_t)b * OVCAP + op] = en;
            }
        }
        if (base + 512 + tid < e_hi) {
            int b = d1 >> 8;
            unsigned int en = ((unsigned int)s1 << 8) | (unsigned int)(d1 & 255);
            int p = atomicAdd(&cnt[b], 1);
            if (p < LCAP) buf[b][p] = en;
            else {
                unsigned int op = atomicAdd(&ovcnt[b * 16], 1u);
                if (op < OVCAP) ovbuf[(size_t)b * OVCAP + op] = en;
            }
        }
        __syncthreads();
        {
            int nb = base + 1024;
            int ea = nb + tid, eb = nb + 512 + tid;
            if (ea < e_hi) { d0 = dst[ea]; s0 = src[ea]; }
            if (eb < e_hi) { d1 = dst[eb]; s1 = src[eb]; }
        }
        for (int b = tid; b < NBUCK; b += 512) {
            int c = cnt[b]; if (c > LCAP) c = LCAP;
            int nf = c & ~15;
            if (nf) {
                unsigned int gb = atomicAdd(&gcur[b * 16], (unsigned int)nf);
                if (gb + (unsigned)nf <= MCAP) {
                    for (int k = 0; k < nf; k += 4) {
                        uint4 v = make_uint4(buf[b][k], buf[b][k + 1],
                                             buf[b][k + 2], buf[b][k + 3]);
                        *(uint4*)&mainr[(size_t)b * MCAP + gb + k] = v;
                    }
                } else {
                    unsigned int op = atomicAdd(&ovcnt[b * 16], (unsigned int)nf);
                    for (int k = 0; k < nf; ++k)
                        if (op + k < OVCAP) ovbuf[(size_t)b * OVCAP + op + k] = buf[b][k];
                }
                int rem = c - nf;
                for (int k = 0; k < rem; ++k) buf[b][k] = buf[b][nf + k];
                cnt[b] = rem;
            } else {
                cnt[b] = c;
            }
        }
        __syncthreads();
    }
    for (int b = tid; b < NBUCK; b += 512) {
        int c = cnt[b]; if (c > LCAP) c = LCAP;
        if (c) {
            unsigned int ob = atomicAdd(&ovcnt[b * 16], (unsigned int)c);
            for (int k = 0; k < c; ++k)
                if (ob + k < OVCAP) ovbuf[(size_t)b * OVCAP + ob + k] = buf[b][k];
        }
    }
}

// ---------------------------------------------------------------- pass 2: per-bucket local CSR build
__global__ __launch_bounds__(256) void build_kernel(const unsigned int* __restrict__ gcur,
                                                    unsigned int* __restrict__ mainr,
                                                    const unsigned int* __restrict__ ovcnt,
                                                    const unsigned int* __restrict__ ovbuf,
                                                    float* __restrict__ dinv,
                                                    int* __restrict__ row_start,
                                                    int* __restrict__ row_end) {
    __shared__ unsigned int stage[STCAP];   // 36 KB
    __shared__ int degl[BS_N];
    __shared__ int rs_l[BS_N];
    __shared__ int curl[BS_N];
    __shared__ int wtot[4];
    int b = blockIdx.x;
    int tid = threadIdx.x;

    int cm = (int)gcur[b * 16]; if (cm > MCAP) cm = MCAP;
    for (int i = tid; i < cm; i += 256) stage[i] = mainr[(size_t)b * MCAP + i];
    int co = (int)ovcnt[b * 16]; if (co > OVCAP) co = OVCAP;
    for (int i = tid; i < co; i += 256) {
        int p = cm + i;
        if (p < STCAP) stage[p] = ovbuf[(size_t)b * OVCAP + i];
    }
    int c = cm + co; if (c > STCAP) c = STCAP;
    degl[tid] = 0;
    __syncthreads();

    for (int i = tid; i < c; i += 256) atomicAdd(&degl[stage[i] & 255], 1);
    __syncthreads();

    int lane = tid & 63, w = tid >> 6;
    int d = degl[tid];
    int x = d;
    #pragma unroll
    for (int off = 1; off < 64; off <<= 1) {
        int y = __shfl_up(x, off);
        if (lane >= off) x += y;
    }
    if (lane == 63) wtot[w] = x;
    __syncthreads();
    int pbase = 0;
    #pragma unroll
    for (int k = 0; k < 4; ++k) if (k < w) pbase += wtot[k];
    rs_l[tid] = pbase + x - d;
    curl[tid] = 0;
    __syncthreads();

    size_t gbase = (size_t)b * MCAP;
    for (int i = tid; i < c; i += 256) {
        unsigned int en = stage[i];
        int dl = en & 255;
        int p = atomicAdd(&curl[dl], 1);
        mainr[gbase + rs_l[dl] + p] = en >> 8;
    }
    int node = b * BS_N + tid;
    if (node < N_NODES) {
        int deg = degl[tid];
        dinv[node] = rsqrtf((float)deg + 1.0f);
        row_start[node] = (int)gbase + rs_l[tid];
        row_end[node] = (int)gbase + rs_l[tid] + deg;
    }
}

// ---------------------------------------------------------------- GEMM 1: [N,128]@[128,64] -> bf16, scaled by dinv
__global__ __launch_bounds__(256) void gemm1_kernel(const float* __restrict__ X,
                                                    const float* __restrict__ W,
                                                    const float* __restrict__ dinv,
                                                    unsigned short* __restrict__ H) {
    __shared__ float Xs[64][68];
    __shared__ float Ws[F_IN * H1];
    int r0 = blockIdx.x * 64;
    const float4* W4 = (const float4*)W;
    float4* Ws4 = (float4*)Ws;
    for (int i = threadIdx.x; i < F_IN * H1 / 4; i += 256) Ws4[i] = W4[i];

    int tx = threadIdx.x & 15;
    int ty = threadIdx.x >> 4;
    float acc[4][4] = {};

    for (int kh = 0; kh < 2; ++kh) {
        __syncthreads();
        for (int it = 0; it < 4; ++it) {
            int idx = threadIdx.x + it * 256;
            int r = idx >> 4, k4 = idx & 15;
            int row = r0 + r;
            float4 v = (row < N_NODES)
                ? ((const float4*)X)[(size_t)row * 32 + kh * 16 + k4]
                : make_float4(0.f, 0.f, 0.f, 0.f);
            *(float4*)&Xs[r][k4 * 4] = v;
        }
        __syncthreads();
        #pragma unroll 8
        for (int k = 0; k < 64; ++k) {
            float4 wb = *(const float4*)&Ws[(kh * 64 + k) * H1 + tx * 4];
            float xa0 = Xs[ty * 4 + 0][k];
            float xa1 = Xs[ty * 4 + 1][k];
            float xa2 = Xs[ty * 4 + 2][k];
            float xa3 = Xs[ty * 4 + 3][k];
            acc[0][0] += xa0 * wb.x; acc[0][1] += xa0 * wb.y; acc[0][2] += xa0 * wb.z; acc[0][3] += xa0 * wb.w;
            acc[1][0] += xa1 * wb.x; acc[1][1] += xa1 * wb.y; acc[1][2] += xa1 * wb.z; acc[1][3] += xa1 * wb.w;
            acc[2][0] += xa2 * wb.x; acc[2][1] += xa2 * wb.y; acc[2][2] += xa2 * wb.z; acc[2][3] += xa2 * wb.w;
            acc[3][0] += xa3 * wb.x; acc[3][1] += xa3 * wb.y; acc[3][2] += xa3 * wb.z; acc[3][3] += xa3 * wb.w;
        }
    }
    #pragma unroll
    for (int i = 0; i < 4; ++i) {
        int row = r0 + ty * 4 + i;
        if (row < N_NODES) {
            float dv = dinv[row];
            unsigned int lo = (unsigned int)f2bf(acc[i][0] * dv) |
                              ((unsigned int)f2bf(acc[i][1] * dv) << 16);
            unsigned int hi = (unsigned int)f2bf(acc[i][2] * dv) |
                              ((unsigned int)f2bf(acc[i][3] * dv) << 16);
            *(uint2*)&H[(size_t)row * H1 + tx * 4] = make_uint2(lo, hi);
        }
    }
}

// ---------------------------------------------------------------- GEMM 2: [N,64]@[64,32] -> bf16, scaled by dinv
__global__ __launch_bounds__(256) void gemm2_kernel(const float* __restrict__ X,
                                                    const float* __restrict__ W,
                                                    const float* __restrict__ dinv,
                                                    unsigned short* __restrict__ H) {
    __shared__ float Xs[64][68];
    __shared__ float Ws[H1 * H2];
    int r0 = blockIdx.x * 64;
    const float4* W4 = (const float4*)W;
    float4* Ws4 = (float4*)Ws;
    for (int i = threadIdx.x; i < H1 * H2 / 4; i += 256) Ws4[i] = W4[i];
    for (int it = 0; it < 4; ++it) {
        int idx = threadIdx.x + it * 256;
        int r = idx >> 4, k4 = idx & 15;
        int row = r0 + r;
        float4 v = (row < N_NODES)
            ? ((const float4*)X)[(size_t)row * 16 + k4]
            : make_float4(0.f, 0.f, 0.f, 0.f);
        *(float4*)&Xs[r][k4 * 4] = v;
    }
    __syncthreads();
    int tx = threadIdx.x & 15;
    int ty = threadIdx.x >> 4;
    float acc[4][2] = {};
    #pragma unroll 8
    for (int k = 0; k < 64; ++k) {
        float2 wb = *(const float2*)&Ws[k * H2 + tx * 2];
        float xa0 = Xs[ty * 4 + 0][k];
        float xa1 = Xs[ty * 4 + 1][k];
        float xa2 = Xs[ty * 4 + 2][k];
        float xa3 = Xs[ty * 4 + 3][k];
        acc[0][0] += xa0 * wb.x; acc[0][1] += xa0 * wb.y;
        acc[1][0] += xa1 * wb.x; acc[1][1] += xa1 * wb.y;
        acc[2][0] += xa2 * wb.x; acc[2][1] += xa2 * wb.y;
        acc[3][0] += xa3 * wb.x; acc[3][1] += xa3 * wb.y;
    }
    #pragma unroll
    for (int i = 0; i < 4; ++i) {
        int row = r0 + ty * 4 + i;
        if (row < N_NODES) {
            float dv = dinv[row];
            unsigned int v = (unsigned int)f2bf(acc[i][0] * dv) |
                             ((unsigned int)f2bf(acc[i][1] * dv) << 16);
            *(unsigned int*)&H[(size_t)row * H2 + tx * 2] = v;
        }
    }
}

// ---------------------------------------------------------------- pull1: wave/node, 8 lanes/edge, uint4 gathers
// lane g=lane>>3 handles edge e+g; sub=lane&7 holds features sub*8..+7
__global__ __launch_bounds__(256) void pull1_kernel(const unsigned short* __restrict__ h,
                                                    const unsigned int* __restrict__ csr,
                                                    const int* __restrict__ row_start,
                                                    const int* __restrict__ row_end,
                                                    const float* __restrict__ dinv,
                                                    const float* __restrict__ b,
                                                    float* __restrict__ xout) {
    int wave = (blockIdx.x * 256 + threadIdx.x) >> 6;   // grid is exact: 25000 blocks
    int lane = threadIdx.x & 63;
    int g = lane >> 3;
    int sub = lane & 7;
    int i = wave;
    int e0 = row_start[i], e1 = row_end[i];
    float acc[8] = {};
    int e = e0;
    // 16 edges/iter: two independent uint4 gathers in flight
    for (; e + 16 <= e1; e += 16) {
        int s0 = csr[e + g];
        int s1 = csr[e + 8 + g];
        uint4 v0 = *(const uint4*)&h[(size_t)s0 * H1 + sub * 8];
        uint4 v1 = *(const uint4*)&h[(size_t)s1 * H1 + sub * 8];
        accp4(acc, v0);
        accp4(acc, v1);
    }
    if (e + 8 <= e1) {
        int s = csr[e + g];
        uint4 v = *(const uint4*)&h[(size_t)s * H1 + sub * 8];
        accp4(acc, v);
        e += 8;
    }
    if (e < e1) {                       // predicated tail (<8 edges)
        int idx = e + g;
        if (idx < e1) {
            int s = csr[idx];
            uint4 v = *(const uint4*)&h[(size_t)s * H1 + sub * 8];
            accp4(acc, v);
        }
    }
    // reduce across the 8 edge-groups (lane bits 3,4,5)
    #pragma unroll
    for (int m = 8; m < 64; m <<= 1) {
        #pragma unroll
        for (int j = 0; j < 8; ++j) acc[j] += __shfl_xor(acc[j], m);
    }
    if (g == 0) {                       // lanes 0..7 finalize features sub*8..+7
        float di = dinv[i];
        uint4 sv = *(const uint4*)&h[(size_t)i * H1 + sub * 8];   // self loop
        accp4(acc, sv);
        float4 o0, o1;
        o0.x = fmaxf(di * acc[0] + b[sub * 8 + 0], 0.0f);
        o0.y = fmaxf(di * acc[1] + b[sub * 8 + 1], 0.0f);
        o0.z = fmaxf(di * acc[2] + b[sub * 8 + 2], 0.0f);
        o0.w = fmaxf(di * acc[3] + b[sub * 8 + 3], 0.0f);
        o1.x = fmaxf(di * acc[4] + b[sub * 8 + 4], 0.0f);
        o1.y = fmaxf(di * acc[5] + b[sub * 8 + 5], 0.0f);
        o1.z = fmaxf(di * acc[6] + b[sub * 8 + 6], 0.0f);
        o1.w = fmaxf(di * acc[7] + b[sub * 8 + 7], 0.0f);
        *(float4*)&xout[(size_t)i * H1 + sub * 8] = o0;
        *(float4*)&xout[(size_t)i * H1 + sub * 8 + 4] = o1;
    }
}

// ---------------------------------------------------------------- pull2: wave/node, 4 lanes/edge, uint4 gathers
// g=lane>>2 handles edge e+g (16/iter); sub=lane&3 holds features sub*8..+7 of 32
__global__ __launch_bounds__(256) void pull2_kernel(const unsigned short* __restrict__ h,
                                                    const unsigned int* __restrict__ csr,
                                                    const int* __restrict__ row_start,
                                                    const int* __restrict__ row_end,
                                                    const float* __restrict__ dinv,
                                                    const float* __restrict__ b,
                                                    float* __restrict__ xout) {
    int wave = (blockIdx.x * 256 + threadIdx.x) >> 6;
    int lane = threadIdx.x & 63;
    int g = lane >> 2;
    int sub = lane & 3;
    int i = wave;
    int e0 = row_start[i], e1 = row_end[i];
    float acc[8] = {};
    int e = e0;
    for (; e + 32 <= e1; e += 32) {     // 32 edges/iter, 2 gathers in flight
        int s0 = csr[e + g];
        int s1 = csr[e + 16 + g];
        uint4 v0 = *(const uint4*)&h[(size_t)s0 * H2 + sub * 8];
        uint4 v1 = *(const uint4*)&h[(size_t)s1 * H2 + sub * 8];
        accp4(acc, v0);
        accp4(acc, v1);
    }
    if (e + 16 <= e1) {
        int s = csr[e + g];
        uint4 v = *(const uint4*)&h[(size_t)s * H2 + sub * 8];
        accp4(acc, v);
        e += 16;
    }
    if (e < e1) {                       // predicated tail (<16 edges)
        int idx = e + g;
        if (idx < e1) {
            int s = csr[idx];
            uint4 v = *(const uint4*)&h[(size_t)s * H2 + sub * 8];
            accp4(acc, v);
        }
    }
    // reduce across the 16 edge-groups (lane bits 2..5)
    #pragma unroll
    for (int m = 4; m < 64; m <<= 1) {
        #pragma unroll
        for (int j = 0; j < 8; ++j) acc[j] += __shfl_xor(acc[j], m);
    }
    if (g == 0) {                       // lanes 0..3 finalize
        float di = dinv[i];
        uint4 sv = *(const uint4*)&h[(size_t)i * H2 + sub * 8];   // self loop
        accp4(acc, sv);
        float4 o0, o1;
        o0.x = fmaxf(di * acc[0] + b[sub * 8 + 0], 0.0f);
        o0.y = fmaxf(di * acc[1] + b[sub * 8 + 1], 0.0f);
        o0.z = fmaxf(di * acc[2] + b[sub * 8 + 2], 0.0f);
        o0.w = fmaxf(di * acc[3] + b[sub * 8 + 3], 0.0f);
        o1.x = fmaxf(di * acc[4] + b[sub * 8 + 4], 0.0f);
        o1.y = fmaxf(di * acc[5] + b[sub * 8 + 5], 0.0f);
        o1.z = fmaxf(di * acc[6] + b[sub * 8 + 6], 0.0f);
        o1.w = fmaxf(di * acc[7] + b[sub * 8 + 7], 0.0f);
        *(float4*)&xout[(size_t)i * H2 + sub * 8] = o0;
        *(float4*)&xout[(size_t)i * H2 + sub * 8 + 4] = o1;
    }
}

// ---------------------------------------------------------------- classifier + log_softmax
__global__ __launch_bounds__(256) void final_kernel(const float* __restrict__ X2,
                                                    const float* __restrict__ Wc,
                                                    const float* __restrict__ bc,
                                                    float* __restrict__ out) {
    __shared__ float Ws[H2 * NCLS];   // 320 floats > 256 threads: loop
    __shared__ float bs[NCLS];
    for (int idx = threadIdx.x; idx < H2 * NCLS; idx += 256) Ws[idx] = Wc[idx];
    if (threadIdx.x < NCLS) bs[threadIdx.x] = bc[threadIdx.x];
    __syncthreads();
    int i = blockIdx.x * blockDim.x + threadIdx.x;
    if (i >= N_NODES) return;
    float x[H2];
    #pragma unroll
    for (int k = 0; k < H2; ++k) x[k] = X2[(size_t)i * H2 + k];
    float lg[NCLS];
    #pragma unroll
    for (int c = 0; c < NCLS; ++c) {
        float acc = bs[c];
        #pragma unroll
        for (int k = 0; k < H2; ++k) acc += x[k] * Ws[k * NCLS + c];
        lg[c] = acc;
    }
    float m = lg[0];
    #pragma unroll
    for (int c = 1; c < NCLS; ++c) m = fmaxf(m, lg[c]);
    float s = 0.0f;
    #pragma unroll
    for (int c = 0; c < NCLS; ++c) s += expf(lg[c] - m);
    float lse = m + logf(s);
    #pragma unroll
    for (int c = 0; c < NCLS; ++c) out[(size_t)i * NCLS + c] = lg[c] - lse;
}

// ----------------------------------------------------------------
extern "C" void kernel_launch(void* const* d_in, const int* in_sizes, int n_in,
                              void* d_out, int out_size, void* d_ws, size_t ws_size,
                              hipStream_t stream) {
    const float* feature = (const float*)d_in[0];
    const int*   eidx    = (const int*)d_in[1];
    const float* W1      = (const float*)d_in[2];
    const float* b1      = (const float*)d_in[3];
    const float* W2      = (const float*)d_in[4];
    const float* b2      = (const float*)d_in[5];
    const float* Wc      = (const float*)d_in[6];
    const float* bc      = (const float*)d_in[7];
    float* out = (float*)d_out;

    const int E = in_sizes[1] / 2;
    const int* src = eidx;
    const int* dst = eidx + E;

    float*          ws        = (float*)d_ws;
    float*          dinv      = ws;
    int*            row_start = (int*)(dinv + N_NODES);
    int*            row_end   = row_start + N_NODES;
    unsigned int*   gcur      = (unsigned int*)(row_end + N_NODES);
    unsigned int*   ovcnt     = gcur + (size_t)NBUCK * 16;
    unsigned int*   ovbuf     = ovcnt + (size_t)NBUCK * 16;
    unsigned int*   mainr     = ovbuf + (size_t)NBUCK * OVCAP;
    unsigned short* h1b       = (unsigned short*)(mainr + (size_t)NBUCK * MCAP);
    float*          x1        = (float*)(h1b + (size_t)N_NODES * H1);
    unsigned short* h2b       = h1b;                 // overlay: h1 dead after pull1
    float*          x2        = x1;                  // overlay: x1 dead after gemm2

    // CSR build
    hipMemsetAsync(gcur, 0, (size_t)NBUCK * 32 * sizeof(unsigned int), stream);
    bin_kernel<<<BIN_WG, 512, 0, stream>>>(src, dst, E, gcur, mainr, ovcnt, ovbuf);
    build_kernel<<<NBUCK, 256, 0, stream>>>(gcur, mainr, ovcnt, ovbuf,
                                            dinv, row_start, row_end);

    // layer 1
    gemm1_kernel<<<(N_NODES + 63) / 64, 256, 0, stream>>>(feature, W1, dinv, h1b);
    {
        unsigned int grid = (unsigned int)(((size_t)N_NODES * 64 + 255) / 256);
        pull1_kernel<<<grid, 256, 0, stream>>>(h1b, mainr, row_start, row_end, dinv, b1, x1);
    }

    // layer 2
    gemm2_kernel<<<(N_NODES + 63) / 64, 256, 0, stream>>>(x1, W2, dinv, h2b);
    {
        unsigned int grid = (unsigned int)(((size_t)N_NODES * 64 + 255) / 256);
        pull2_kernel<<<grid, 256, 0, stream>>>(h2b, mainr, row_start, row_end, dinv, b2, x2);
    }

    // classifier + log_softmax
    final_kernel<<<(N_NODES + 255) / 256, 256, 0, stream>>>(x2, Wc, bc, out);
}